// Round 4
// baseline (2301.118 us; speedup 1.0000x reference)
//
#include <hip/hip_runtime.h>
#include <hip/hip_bf16.h>
#include <cstdint>
#include <cstddef>

#define F_IN 126
#define HID 256

// ---------------------------------------------------------------- utilities

__global__ void hist_kernel(const int* __restrict__ dst, int E, int* __restrict__ cnt) {
  int e = blockIdx.x * blockDim.x + threadIdx.x;
  if (e < E) atomicAdd(&cnt[dst[e]], 1);
}

__global__ void dinv_kernel(const int* __restrict__ cnt, float* __restrict__ dinv, int N) {
  int i = blockIdx.x * blockDim.x + threadIdx.x;
  if (i < N) dinv[i] = rsqrtf((float)(cnt[i] + 1));  // self-loop => deg >= 1
}

// exclusive scan over cnt[0..N) -> rowstart, 3-kernel (local, block sums, add-back)
__global__ void scan_local(const int* __restrict__ cnt, int* __restrict__ rowstart,
                           int* __restrict__ blocksum, int N) {
  __shared__ int sd[1024];
  int t = threadIdx.x;
  int gi = blockIdx.x * 1024 + t;
  int v = (gi < N) ? cnt[gi] : 0;
  sd[t] = v;
  __syncthreads();
  for (int off = 1; off < 1024; off <<= 1) {
    int add = (t >= off) ? sd[t - off] : 0;
    __syncthreads();
    sd[t] += add;
    __syncthreads();
  }
  if (gi < N) rowstart[gi] = sd[t] - v;   // exclusive within block
  if (t == 1023) blocksum[blockIdx.x] = sd[1023];
}

__global__ void scan_blk(const int* __restrict__ blocksum, int* __restrict__ blockoff, int nblk) {
  __shared__ int sd[128];
  int t = threadIdx.x;
  int v = (t < nblk) ? blocksum[t] : 0;
  sd[t] = v;
  __syncthreads();
  for (int off = 1; off < 128; off <<= 1) {
    int add = (t >= off) ? sd[t - off] : 0;
    __syncthreads();
    sd[t] += add;
    __syncthreads();
  }
  if (t < nblk) blockoff[t] = sd[t] - v;
}

__global__ void scan_add(int* __restrict__ rowstart, const int* __restrict__ blockoff,
                         int* __restrict__ cursor, int N, int E) {
  int i = blockIdx.x * blockDim.x + threadIdx.x;
  if (i < N) {
    int r = rowstart[i] + blockoff[i >> 10];
    rowstart[i] = r;
    cursor[i] = r;
  }
  if (i == 0) rowstart[N] = E;
}

__global__ void fill_csr(const int* __restrict__ srcp, const int* __restrict__ dstp,
                         const float* __restrict__ dinv, int* __restrict__ cursor,
                         int* __restrict__ col, float* __restrict__ val, int E) {
  int e = blockIdx.x * blockDim.x + threadIdx.x;
  if (e >= E) return;
  int s = srcp[e];
  int d = dstp[e];
  int pos = atomicAdd(&cursor[d], 1);
  col[pos] = s;
  val[pos] = dinv[s] * dinv[d];
}

// c[n] = u*W1[126,n] + w*W1[127,n]  (the constant [u,w] feature columns folded out)
__global__ void c_kernel(const float* __restrict__ W1, const float* __restrict__ up,
                         const float* __restrict__ wp, float* __restrict__ c) {
  int n = threadIdx.x;
  c[n] = up[0] * W1[126 * 256 + n] + wp[0] * W1[127 * 256 + n];
}

// x [N,126] -> X [N,128] zero-padded (cols 126,127 = 0)
__global__ void padx_kernel(const float* __restrict__ x, float* __restrict__ X, int N) {
  long long i = (long long)blockIdx.x * blockDim.x + threadIdx.x;
  if (i >= (long long)N * 128) return;
  int r = (int)(i >> 7), f = (int)(i & 127);
  X[i] = (f < F_IN) ? x[(size_t)r * F_IN + f] : 0.0f;
}

// ---------------------------------------------------------------- SpMM (CSR, wave per row)

__global__ __launch_bounds__(256) void spmm_kernel_128(
    const float* __restrict__ H, const int* __restrict__ rowstart,
    const int* __restrict__ col, const float* __restrict__ val,
    const float* __restrict__ dinv, float* __restrict__ G,
    float* __restrict__ svec, int N)
{
  int wave = threadIdx.x >> 6, lane = threadIdx.x & 63;
  int row = blockIdx.x * 4 + wave;
  if (row >= N) return;
  float dv = dinv[row];
  float self = dv * dv;
  float2 acc = *(const float2*)(H + (size_t)row * 128 + lane * 2);
  acc.x *= self; acc.y *= self;
  float vsum = self;
  int e0 = rowstart[row], e1 = rowstart[row + 1];
  for (int e = e0; e < e1; ++e) {
    int sc = col[e];
    float v = val[e];
    float2 hv = *(const float2*)(H + (size_t)sc * 128 + lane * 2);
    acc.x = fmaf(v, hv.x, acc.x);
    acc.y = fmaf(v, hv.y, acc.y);
    vsum += v;
  }
  *(float2*)(G + (size_t)row * 128 + lane * 2) = acc;
  if (lane == 0) svec[row] = vsum;   // s = rowsum of A_hat (for the u,w columns)
}

__global__ __launch_bounds__(256) void spmm_kernel_256(
    const float* __restrict__ H, const int* __restrict__ rowstart,
    const int* __restrict__ col, const float* __restrict__ val,
    const float* __restrict__ dinv, float* __restrict__ G, int N)
{
  int wave = threadIdx.x >> 6, lane = threadIdx.x & 63;
  int row = blockIdx.x * 4 + wave;
  if (row >= N) return;
  float dv = dinv[row];
  float self = dv * dv;
  float4 acc = *(const float4*)(H + (size_t)row * 256 + lane * 4);
  acc.x *= self; acc.y *= self; acc.z *= self; acc.w *= self;
  int e0 = rowstart[row], e1 = rowstart[row + 1];
  for (int e = e0; e < e1; ++e) {
    int sc = col[e];
    float v = val[e];
    float4 hv = *(const float4*)(H + (size_t)sc * 256 + lane * 4);
    acc.x = fmaf(v, hv.x, acc.x);
    acc.y = fmaf(v, hv.y, acc.y);
    acc.z = fmaf(v, hv.z, acc.z);
    acc.w = fmaf(v, hv.w, acc.w);
  }
  *(float4*)(G + (size_t)row * 256 + lane * 4) = acc;
}

// ---------------------------------------------------------------- GEMM + bias + leaky-relu
// out[N,256] = act(A[N,K] @ W[K,256] + bias + (useS ? s[i]*c[n] : 0))
// 128x128 tile, BK=32, 256 threads, 8x8 per thread.

__global__ __launch_bounds__(256) void gemm_bias_act(
    const float* __restrict__ A, const float* __restrict__ W,
    const float* __restrict__ bias, const float* __restrict__ s,
    const float* __restrict__ c, float* __restrict__ out,
    int N, int K, int useS)
{
  __shared__ float As[32][132];
  __shared__ float Bs[32][132];
  int t = threadIdx.x;
  int tx = t & 15, ty = t >> 4;
  int row0 = blockIdx.x * 128, col0 = blockIdx.y * 128;
  float acc[8][8] = {};
  for (int kc = 0; kc < K; kc += 32) {
    // A tile: 128 rows x 32 k, transposed into As[k][m]
    #pragma unroll
    for (int l = 0; l < 4; ++l) {
      int f4 = t + l * 256;
      int m = f4 >> 3;
      int kk = (f4 & 7) << 2;
      int row = row0 + m;
      float4 v = make_float4(0.f, 0.f, 0.f, 0.f);
      if (row < N) v = *(const float4*)(A + (size_t)row * K + kc + kk);
      As[kk + 0][m] = v.x; As[kk + 1][m] = v.y; As[kk + 2][m] = v.z; As[kk + 3][m] = v.w;
    }
    // B tile: 32 k x 128 n, natural layout
    #pragma unroll
    for (int l = 0; l < 4; ++l) {
      int f4 = t + l * 256;
      int kr = f4 >> 5;
      int nn = (f4 & 31) << 2;
      *(float4*)&Bs[kr][nn] = *(const float4*)(W + (size_t)(kc + kr) * 256 + col0 + nn);
    }
    __syncthreads();
    #pragma unroll
    for (int k = 0; k < 32; ++k) {
      float a[8], b[8];
      *(float4*)&a[0] = *(const float4*)&As[k][ty * 8];
      *(float4*)&a[4] = *(const float4*)&As[k][ty * 8 + 4];
      *(float4*)&b[0] = *(const float4*)&Bs[k][tx * 8];
      *(float4*)&b[4] = *(const float4*)&Bs[k][tx * 8 + 4];
      #pragma unroll
      for (int i = 0; i < 8; ++i)
        #pragma unroll
        for (int j = 0; j < 8; ++j)
          acc[i][j] = fmaf(a[i], b[j], acc[i][j]);
    }
    __syncthreads();
  }
  float bb[8], ccv[8];
  #pragma unroll
  for (int j = 0; j < 8; ++j) {
    bb[j] = bias[col0 + tx * 8 + j];
    ccv[j] = useS ? c[col0 + tx * 8 + j] : 0.0f;
  }
  #pragma unroll
  for (int i = 0; i < 8; ++i) {
    int row = row0 + ty * 8 + i;
    if (row < N) {
      float sv = useS ? s[row] : 0.0f;
      float o[8];
      #pragma unroll
      for (int j = 0; j < 8; ++j) {
        float v2 = acc[i][j] + bb[j] + sv * ccv[j];
        o[j] = v2 > 0.0f ? v2 : 0.01f * v2;
      }
      *(float4*)(out + (size_t)row * 256 + col0 + tx * 8)     = *(float4*)&o[0];
      *(float4*)(out + (size_t)row * 256 + col0 + tx * 8 + 4) = *(float4*)&o[4];
    }
  }
}

// ---------------------------------------------------------------- pooling + head

__global__ void colsum_kernel(const float* __restrict__ H, float* __restrict__ pooled, int N) {
  int t = threadIdx.x;
  float acc = 0.f;
  for (int r = blockIdx.x; r < N; r += gridDim.x)
    acc += H[(size_t)r * 256 + t];
  atomicAdd(&pooled[t], acc);
}

__global__ void final_kernel(const float* __restrict__ pooled, const float* __restrict__ Wlin,
                             const float* __restrict__ blin, float* __restrict__ out, float invN) {
  __shared__ float sd[256];
  int t = threadIdx.x;
  sd[t] = pooled[t] * invN * Wlin[t];
  __syncthreads();
  for (int off = 128; off > 0; off >>= 1) {
    if (t < off) sd[t] += sd[t + off];
    __syncthreads();
  }
  if (t == 0) out[0] = sd[0] + blin[0];
}

// ---------------------------------------------------------------- launch

extern "C" void kernel_launch(void* const* d_in, const int* in_sizes, int n_in,
                              void* d_out, int out_size, void* d_ws, size_t ws_size,
                              hipStream_t stream) {
  const float* x    = (const float*)d_in[0];
  const int*   ei   = (const int*)d_in[1];     // int32 on the wire (JAX x64 disabled)
  const float* u    = (const float*)d_in[2];
  const float* w    = (const float*)d_in[3];
  const float* W1   = (const float*)d_in[4];  const float* b1 = (const float*)d_in[5];
  const float* W2   = (const float*)d_in[6];  const float* b2 = (const float*)d_in[7];
  const float* W3   = (const float*)d_in[8];  const float* b3 = (const float*)d_in[9];
  const float* W4   = (const float*)d_in[10]; const float* b4 = (const float*)d_in[11];
  const float* W5   = (const float*)d_in[12]; const float* b5 = (const float*)d_in[13];
  const float* Wlin = (const float*)d_in[14]; const float* blin = (const float*)d_in[15];

  int N = in_sizes[0] / F_IN;
  int E = in_sizes[1] / 2;
  const int* srcp = ei;
  const int* dstp = ei + E;

  char* p = (char*)d_ws;
  auto alloc = [&](size_t bytes) { char* r = p; p += (bytes + 255) & ~(size_t)255; return r; };
  float* bufH     = (float*)alloc((size_t)N * 256 * 4);
  float* bufG     = (float*)alloc((size_t)N * 256 * 4);
  int*   colA     = (int*)alloc((size_t)E * 4);
  float* valA     = (float*)alloc((size_t)E * 4);
  int*   cnt      = (int*)alloc((size_t)N * 4);
  float* dinv     = (float*)alloc((size_t)N * 4);
  int*   rowstart = (int*)alloc((size_t)(N + 1) * 4);
  int*   cursor   = (int*)alloc((size_t)N * 4);
  float* svec     = (float*)alloc((size_t)N * 4);
  float* cvec     = (float*)alloc(256 * 4);
  int*   blocksum = (int*)alloc(128 * 4);
  int*   blockoff = (int*)alloc(128 * 4);
  float* pooled   = (float*)alloc(256 * 4);

  hipMemsetAsync(cnt, 0, (size_t)N * 4, stream);
  hipMemsetAsync(pooled, 0, 256 * 4, stream);

  const int tpb = 256;
  hist_kernel<<<(E + tpb - 1) / tpb, tpb, 0, stream>>>(dstp, E, cnt);
  dinv_kernel<<<(N + tpb - 1) / tpb, tpb, 0, stream>>>(cnt, dinv, N);
  int nblk = (N + 1023) / 1024;
  scan_local<<<nblk, 1024, 0, stream>>>(cnt, rowstart, blocksum, N);
  scan_blk<<<1, 128, 0, stream>>>(blocksum, blockoff, nblk);
  scan_add<<<(N + tpb - 1) / tpb, tpb, 0, stream>>>(rowstart, blockoff, cursor, N, E);
  fill_csr<<<(E + tpb - 1) / tpb, tpb, 0, stream>>>(srcp, dstp, dinv, cursor, colA, valA, E);
  c_kernel<<<1, 256, 0, stream>>>(W1, u, w, cvec);

  long long nx = (long long)N * 128;
  padx_kernel<<<(int)((nx + tpb - 1) / tpb), tpb, 0, stream>>>(x, bufH, N);

  dim3 ggrid((N + 127) / 128, 2);
  // layer 1: aggregate at width 128, then transform 128->256 with s*c epilogue
  spmm_kernel_128<<<(N + 3) / 4, 256, 0, stream>>>(bufH, rowstart, colA, valA, dinv, bufG, svec, N);
  gemm_bias_act<<<ggrid, 256, 0, stream>>>(bufG, W1, b1, svec, cvec, bufH, N, 128, 1);

  const float* Ws[4] = {W2, W3, W4, W5};
  const float* bs[4] = {b2, b3, b4, b5};
  for (int l = 0; l < 4; ++l) {
    spmm_kernel_256<<<(N + 3) / 4, 256, 0, stream>>>(bufH, rowstart, colA, valA, dinv, bufG, N);
    gemm_bias_act<<<ggrid, 256, 0, stream>>>(bufG, Ws[l], bs[l], svec, cvec, bufH, N, 256, 0);
  }

  colsum_kernel<<<2048, 256, 0, stream>>>(bufH, pooled, N);
  final_kernel<<<1, 256, 0, stream>>>(pooled, Wlin, blin, (float*)d_out, 1.0f / (float)N);
}

// Round 5
// 2105.600 us; speedup vs baseline: 1.0929x; 1.0929x over previous
//
#include <hip/hip_runtime.h>
#include <hip/hip_bf16.h>
#include <cstdint>
#include <cstddef>

#define F_IN 126
#define HID 256

// bf16 storage helpers (arithmetic stays fp32)
__device__ __forceinline__ float bf2f(unsigned short u) {
  union { unsigned int i; float f; } v; v.i = ((unsigned int)u) << 16; return v.f;
}
__device__ __forceinline__ unsigned short f2bf(float x) {
  union { float f; unsigned int i; } v; v.f = x;
  unsigned int b = v.i + 0x7FFFu + ((v.i >> 16) & 1u);  // round-to-nearest-even
  return (unsigned short)(b >> 16);
}

// ---------------------------------------------------------------- graph prep

__global__ void hist_kernel(const int* __restrict__ dst, int E, int* __restrict__ cnt) {
  int e = blockIdx.x * blockDim.x + threadIdx.x;
  if (e < E) atomicAdd(&cnt[dst[e]], 1);
}

__global__ void dinv_kernel(const int* __restrict__ cnt, float* __restrict__ dinv, int N) {
  int i = blockIdx.x * blockDim.x + threadIdx.x;
  if (i < N) dinv[i] = rsqrtf((float)(cnt[i] + 1));  // self-loop => deg >= 1
}

__global__ void scan_local(const int* __restrict__ cnt, int* __restrict__ rowstart,
                           int* __restrict__ blocksum, int N) {
  __shared__ int sd[1024];
  int t = threadIdx.x;
  int gi = blockIdx.x * 1024 + t;
  int v = (gi < N) ? cnt[gi] : 0;
  sd[t] = v;
  __syncthreads();
  for (int off = 1; off < 1024; off <<= 1) {
    int add = (t >= off) ? sd[t - off] : 0;
    __syncthreads();
    sd[t] += add;
    __syncthreads();
  }
  if (gi < N) rowstart[gi] = sd[t] - v;
  if (t == 1023) blocksum[blockIdx.x] = sd[1023];
}

__global__ void scan_blk(const int* __restrict__ blocksum, int* __restrict__ blockoff, int nblk) {
  __shared__ int sd[128];
  int t = threadIdx.x;
  int v = (t < nblk) ? blocksum[t] : 0;
  sd[t] = v;
  __syncthreads();
  for (int off = 1; off < 128; off <<= 1) {
    int add = (t >= off) ? sd[t - off] : 0;
    __syncthreads();
    sd[t] += add;
    __syncthreads();
  }
  if (t < nblk) blockoff[t] = sd[t] - v;
}

__global__ void scan_add(int* __restrict__ rowstart, const int* __restrict__ blockoff,
                         int* __restrict__ cursor, int N, int E) {
  int i = blockIdx.x * blockDim.x + threadIdx.x;
  if (i < N) {
    int r = rowstart[i] + blockoff[i >> 10];
    rowstart[i] = r;
    cursor[i] = r;
  }
  if (i == 0) rowstart[N] = E;
}

__global__ void fill_csr(const int* __restrict__ srcp, const int* __restrict__ dstp,
                         const float* __restrict__ dinv, int* __restrict__ cursor,
                         int* __restrict__ col, float* __restrict__ val, int E) {
  int e = blockIdx.x * blockDim.x + threadIdx.x;
  if (e >= E) return;
  int s = srcp[e];
  int d = dstp[e];
  int pos = atomicAdd(&cursor[d], 1);
  col[pos] = s;
  val[pos] = dinv[s] * dinv[d];
}

// c[n] = u*W1[126,n] + w*W1[127,n]
__global__ void c_kernel(const float* __restrict__ W1, const float* __restrict__ up,
                         const float* __restrict__ wp, float* __restrict__ c) {
  int n = threadIdx.x;
  c[n] = up[0] * W1[126 * 256 + n] + wp[0] * W1[127 * 256 + n];
}

// x [N,126] fp32 -> X [N,128] bf16, zero-padded
__global__ void padx_kernel(const float* __restrict__ x, unsigned short* __restrict__ X, int N) {
  long long i = (long long)blockIdx.x * blockDim.x + threadIdx.x;
  if (i >= (long long)N * 128) return;
  int r = (int)(i >> 7), f = (int)(i & 127);
  X[i] = (f < F_IN) ? f2bf(x[(size_t)r * F_IN + f]) : (unsigned short)0;
}

// ---------------------------------------------------------------- SpMM (CSR, wave per row, bf16 in, fp32 out)

__global__ __launch_bounds__(256) void spmm_kernel_128(
    const unsigned short* __restrict__ H, const int* __restrict__ rowstart,
    const int* __restrict__ col, const float* __restrict__ val,
    const float* __restrict__ dinv, float* __restrict__ G,
    float* __restrict__ svec, int N)
{
  int wave = threadIdx.x >> 6, lane = threadIdx.x & 63;
  int row = blockIdx.x * 4 + wave;
  if (row >= N) return;
  float dv = dinv[row];
  float self = dv * dv;
  unsigned int sv0 = *(const unsigned int*)(H + (size_t)row * 128 + lane * 2);
  float2 acc;
  acc.x = self * bf2f((unsigned short)(sv0 & 0xFFFF));
  acc.y = self * bf2f((unsigned short)(sv0 >> 16));
  float vsum = self;
  int e0 = rowstart[row], e1 = rowstart[row + 1];
  for (int e = e0; e < e1; ++e) {
    int sc = col[e];
    float v = val[e];
    unsigned int hv = *(const unsigned int*)(H + (size_t)sc * 128 + lane * 2);
    acc.x = fmaf(v, bf2f((unsigned short)(hv & 0xFFFF)), acc.x);
    acc.y = fmaf(v, bf2f((unsigned short)(hv >> 16)), acc.y);
    vsum += v;
  }
  *(float2*)(G + (size_t)row * 128 + lane * 2) = acc;
  if (lane == 0) svec[row] = vsum;
}

__global__ __launch_bounds__(256) void spmm_kernel_256(
    const unsigned short* __restrict__ H, const int* __restrict__ rowstart,
    const int* __restrict__ col, const float* __restrict__ val,
    const float* __restrict__ dinv, float* __restrict__ G, int N)
{
  int wave = threadIdx.x >> 6, lane = threadIdx.x & 63;
  int row = blockIdx.x * 4 + wave;
  if (row >= N) return;
  float dv = dinv[row];
  float self = dv * dv;
  uint2 sv0 = *(const uint2*)(H + (size_t)row * 256 + lane * 4);
  float4 acc;
  acc.x = self * bf2f((unsigned short)(sv0.x & 0xFFFF));
  acc.y = self * bf2f((unsigned short)(sv0.x >> 16));
  acc.z = self * bf2f((unsigned short)(sv0.y & 0xFFFF));
  acc.w = self * bf2f((unsigned short)(sv0.y >> 16));
  int e0 = rowstart[row], e1 = rowstart[row + 1];
  for (int e = e0; e < e1; ++e) {
    int sc = col[e];
    float v = val[e];
    uint2 hv = *(const uint2*)(H + (size_t)sc * 256 + lane * 4);
    acc.x = fmaf(v, bf2f((unsigned short)(hv.x & 0xFFFF)), acc.x);
    acc.y = fmaf(v, bf2f((unsigned short)(hv.x >> 16)), acc.y);
    acc.z = fmaf(v, bf2f((unsigned short)(hv.y & 0xFFFF)), acc.z);
    acc.w = fmaf(v, bf2f((unsigned short)(hv.y >> 16)), acc.w);
  }
  *(float4*)(G + (size_t)row * 256 + lane * 4) = acc;
}

// ---------------------------------------------------------------- GEMM + bias + leaky-relu (fp32 compute, bf16 out)
// out[N,256] = act(A[N,K] @ W[K,256] + bias + (useS ? s[i]*c[n] : 0))

__global__ __launch_bounds__(256) void gemm_bias_act(
    const float* __restrict__ A, const float* __restrict__ W,
    const float* __restrict__ bias, const float* __restrict__ s,
    const float* __restrict__ c, unsigned short* __restrict__ out,
    int N, int K, int useS)
{
  __shared__ float As[32][132];
  __shared__ float Bs[32][132];
  int t = threadIdx.x;
  int tx = t & 15, ty = t >> 4;
  int row0 = blockIdx.x * 128, col0 = blockIdx.y * 128;
  float acc[8][8] = {};
  for (int kc = 0; kc < K; kc += 32) {
    #pragma unroll
    for (int l = 0; l < 4; ++l) {
      int f4 = t + l * 256;
      int m = f4 >> 3;
      int kk = (f4 & 7) << 2;
      int row = row0 + m;
      float4 v = make_float4(0.f, 0.f, 0.f, 0.f);
      if (row < N) v = *(const float4*)(A + (size_t)row * K + kc + kk);
      As[kk + 0][m] = v.x; As[kk + 1][m] = v.y; As[kk + 2][m] = v.z; As[kk + 3][m] = v.w;
    }
    #pragma unroll
    for (int l = 0; l < 4; ++l) {
      int f4 = t + l * 256;
      int kr = f4 >> 5;
      int nn = (f4 & 31) << 2;
      *(float4*)&Bs[kr][nn] = *(const float4*)(W + (size_t)(kc + kr) * 256 + col0 + nn);
    }
    __syncthreads();
    #pragma unroll
    for (int k = 0; k < 32; ++k) {
      float a[8], b[8];
      *(float4*)&a[0] = *(const float4*)&As[k][ty * 8];
      *(float4*)&a[4] = *(const float4*)&As[k][ty * 8 + 4];
      *(float4*)&b[0] = *(const float4*)&Bs[k][tx * 8];
      *(float4*)&b[4] = *(const float4*)&Bs[k][tx * 8 + 4];
      #pragma unroll
      for (int i = 0; i < 8; ++i)
        #pragma unroll
        for (int j = 0; j < 8; ++j)
          acc[i][j] = fmaf(a[i], b[j], acc[i][j]);
    }
    __syncthreads();
  }
  float bb[8], ccv[8];
  #pragma unroll
  for (int j = 0; j < 8; ++j) {
    bb[j] = bias[col0 + tx * 8 + j];
    ccv[j] = useS ? c[col0 + tx * 8 + j] : 0.0f;
  }
  #pragma unroll
  for (int i = 0; i < 8; ++i) {
    int row = row0 + ty * 8 + i;
    if (row < N) {
      float sv = useS ? s[row] : 0.0f;
      unsigned int o[4];
      #pragma unroll
      for (int j = 0; j < 4; ++j) {
        float v0 = acc[i][2 * j]     + bb[2 * j]     + sv * ccv[2 * j];
        float v1 = acc[i][2 * j + 1] + bb[2 * j + 1] + sv * ccv[2 * j + 1];
        v0 = v0 > 0.0f ? v0 : 0.01f * v0;
        v1 = v1 > 0.0f ? v1 : 0.01f * v1;
        o[j] = (unsigned int)f2bf(v0) | ((unsigned int)f2bf(v1) << 16);
      }
      *(uint4*)(out + (size_t)row * 256 + col0 + tx * 8) = *(uint4*)&o[0];
    }
  }
}

// ---------------------------------------------------------------- pooling + head

__global__ void colsum_kernel(const unsigned short* __restrict__ H, float* __restrict__ pooled, int N) {
  int t = threadIdx.x;
  float acc = 0.f;
  for (int r = blockIdx.x; r < N; r += gridDim.x)
    acc += bf2f(H[(size_t)r * 256 + t]);
  atomicAdd(&pooled[t], acc);
}

__global__ void final_kernel(const float* __restrict__ pooled, const float* __restrict__ Wlin,
                             const float* __restrict__ blin, float* __restrict__ out, float invN) {
  __shared__ float sd[256];
  int t = threadIdx.x;
  sd[t] = pooled[t] * invN * Wlin[t];
  __syncthreads();
  for (int off = 128; off > 0; off >>= 1) {
    if (t < off) sd[t] += sd[t + off];
    __syncthreads();
  }
  if (t == 0) out[0] = sd[0] + blin[0];
}

// ---------------------------------------------------------------- launch

extern "C" void kernel_launch(void* const* d_in, const int* in_sizes, int n_in,
                              void* d_out, int out_size, void* d_ws, size_t ws_size,
                              hipStream_t stream) {
  const float* x    = (const float*)d_in[0];
  const int*   ei   = (const int*)d_in[1];     // int32 on the wire
  const float* u    = (const float*)d_in[2];
  const float* w    = (const float*)d_in[3];
  const float* W1   = (const float*)d_in[4];  const float* b1 = (const float*)d_in[5];
  const float* W2   = (const float*)d_in[6];  const float* b2 = (const float*)d_in[7];
  const float* W3   = (const float*)d_in[8];  const float* b3 = (const float*)d_in[9];
  const float* W4   = (const float*)d_in[10]; const float* b4 = (const float*)d_in[11];
  const float* W5   = (const float*)d_in[12]; const float* b5 = (const float*)d_in[13];
  const float* Wlin = (const float*)d_in[14]; const float* blin = (const float*)d_in[15];

  int N = in_sizes[0] / F_IN;
  int E = in_sizes[1] / 2;
  const int* srcp = ei;
  const int* dstp = ei + E;

  char* p = (char*)d_ws;
  auto alloc = [&](size_t bytes) { char* r = p; p += (bytes + 255) & ~(size_t)255; return r; };
  unsigned short* bufH = (unsigned short*)alloc((size_t)N * 256 * 2);  // bf16 hidden
  float* bufG     = (float*)alloc((size_t)N * 256 * 4);                // fp32 aggregate
  int*   colA     = (int*)alloc((size_t)E * 4);
  float* valA     = (float*)alloc((size_t)E * 4);
  int*   cnt      = (int*)alloc((size_t)N * 4);
  float* dinv     = (float*)alloc((size_t)N * 4);
  int*   rowstart = (int*)alloc((size_t)(N + 1) * 4);
  int*   cursor   = (int*)alloc((size_t)N * 4);
  float* svec     = (float*)alloc((size_t)N * 4);
  float* cvec     = (float*)alloc(256 * 4);
  int*   blocksum = (int*)alloc(128 * 4);
  int*   blockoff = (int*)alloc(128 * 4);
  float* pooled   = (float*)alloc(256 * 4);

  hipMemsetAsync(cnt, 0, (size_t)N * 4, stream);
  hipMemsetAsync(pooled, 0, 256 * 4, stream);

  const int tpb = 256;
  hist_kernel<<<(E + tpb - 1) / tpb, tpb, 0, stream>>>(dstp, E, cnt);
  dinv_kernel<<<(N + tpb - 1) / tpb, tpb, 0, stream>>>(cnt, dinv, N);
  int nblk = (N + 1023) / 1024;
  scan_local<<<nblk, 1024, 0, stream>>>(cnt, rowstart, blocksum, N);
  scan_blk<<<1, 128, 0, stream>>>(blocksum, blockoff, nblk);
  scan_add<<<(N + tpb - 1) / tpb, tpb, 0, stream>>>(rowstart, blockoff, cursor, N, E);
  fill_csr<<<(E + tpb - 1) / tpb, tpb, 0, stream>>>(srcp, dstp, dinv, cursor, colA, valA, E);
  c_kernel<<<1, 256, 0, stream>>>(W1, u, w, cvec);

  long long nx = (long long)N * 128;
  padx_kernel<<<(int)((nx + tpb - 1) / tpb), tpb, 0, stream>>>(x, bufH, N);

  dim3 ggrid((N + 127) / 128, 2);
  // layer 1: aggregate at width 128 (bf16 gather), transform 128->256 with s*c epilogue
  spmm_kernel_128<<<(N + 3) / 4, 256, 0, stream>>>(bufH, rowstart, colA, valA, dinv, bufG, svec, N);
  gemm_bias_act<<<ggrid, 256, 0, stream>>>(bufG, W1, b1, svec, cvec, bufH, N, 128, 1);

  const float* Ws[4] = {W2, W3, W4, W5};
  const float* bs[4] = {b2, b3, b4, b5};
  for (int l = 0; l < 4; ++l) {
    spmm_kernel_256<<<(N + 3) / 4, 256, 0, stream>>>(bufH, rowstart, colA, valA, dinv, bufG, N);
    gemm_bias_act<<<ggrid, 256, 0, stream>>>(bufG, Ws[l], bs[l], svec, cvec, bufH, N, 256, 0);
  }

  colsum_kernel<<<2048, 256, 0, stream>>>(bufH, pooled, N);
  final_kernel<<<1, 256, 0, stream>>>(pooled, Wlin, blin, (float*)d_out, 1.0f / (float)N);
}

// Round 6
// 1633.231 us; speedup vs baseline: 1.4089x; 1.2892x over previous
//
#include <hip/hip_runtime.h>
#include <hip/hip_bf16.h>
#include <cstdint>
#include <cstddef>

#define F_IN 126
#define HID 256

typedef __attribute__((ext_vector_type(8))) short bf16x8;
typedef __attribute__((ext_vector_type(4))) float f32x4;

// bf16 storage helpers (arithmetic stays fp32)
__device__ __forceinline__ float bf2f(unsigned short u) {
  union { unsigned int i; float f; } v; v.i = ((unsigned int)u) << 16; return v.f;
}
__device__ __forceinline__ unsigned short f2bf(float x) {
  union { float f; unsigned int i; } v; v.f = x;
  unsigned int b = v.i + 0x7FFFu + ((v.i >> 16) & 1u);  // round-to-nearest-even
  return (unsigned short)(b >> 16);
}

// ---------------------------------------------------------------- graph prep

__global__ void hist_kernel(const int* __restrict__ dst, int E, int* __restrict__ cnt) {
  int e = blockIdx.x * blockDim.x + threadIdx.x;
  if (e < E) atomicAdd(&cnt[dst[e]], 1);
}

__global__ void dinv_kernel(const int* __restrict__ cnt, float* __restrict__ dinv, int N) {
  int i = blockIdx.x * blockDim.x + threadIdx.x;
  if (i < N) dinv[i] = rsqrtf((float)(cnt[i] + 1));  // self-loop => deg >= 1
}

__global__ void scan_local(const int* __restrict__ cnt, int* __restrict__ rowstart,
                           int* __restrict__ blocksum, int N) {
  __shared__ int sd[1024];
  int t = threadIdx.x;
  int gi = blockIdx.x * 1024 + t;
  int v = (gi < N) ? cnt[gi] : 0;
  sd[t] = v;
  __syncthreads();
  for (int off = 1; off < 1024; off <<= 1) {
    int add = (t >= off) ? sd[t - off] : 0;
    __syncthreads();
    sd[t] += add;
    __syncthreads();
  }
  if (gi < N) rowstart[gi] = sd[t] - v;
  if (t == 1023) blocksum[blockIdx.x] = sd[1023];
}

__global__ void scan_blk(const int* __restrict__ blocksum, int* __restrict__ blockoff, int nblk) {
  __shared__ int sd[128];
  int t = threadIdx.x;
  int v = (t < nblk) ? blocksum[t] : 0;
  sd[t] = v;
  __syncthreads();
  for (int off = 1; off < 128; off <<= 1) {
    int add = (t >= off) ? sd[t - off] : 0;
    __syncthreads();
    sd[t] += add;
    __syncthreads();
  }
  if (t < nblk) blockoff[t] = sd[t] - v;
}

__global__ void scan_add(int* __restrict__ rowstart, const int* __restrict__ blockoff,
                         int* __restrict__ cursor, int N, int E) {
  int i = blockIdx.x * blockDim.x + threadIdx.x;
  if (i < N) {
    int r = rowstart[i] + blockoff[i >> 10];
    rowstart[i] = r;
    cursor[i] = r;
  }
  if (i == 0) rowstart[N] = E;
}

__global__ void fill_csr(const int* __restrict__ srcp, const int* __restrict__ dstp,
                         const float* __restrict__ dinv, int* __restrict__ cursor,
                         int* __restrict__ col, float* __restrict__ val, int E) {
  int e = blockIdx.x * blockDim.x + threadIdx.x;
  if (e >= E) return;
  int s = srcp[e];
  int d = dstp[e];
  int pos = atomicAdd(&cursor[d], 1);
  col[pos] = s;
  val[pos] = dinv[s] * dinv[d];
}

// c[n] = u*W1[126,n] + w*W1[127,n]
__global__ void c_kernel(const float* __restrict__ W1, const float* __restrict__ up,
                         const float* __restrict__ wp, float* __restrict__ c) {
  int n = threadIdx.x;
  c[n] = up[0] * W1[126 * 256 + n] + wp[0] * W1[127 * 256 + n];
}

// W [K,256] fp32 -> WtHi/WtLo [256,K] bf16 (transposed, hi + residual-lo split)
__global__ void wt_split(const float* __restrict__ W, unsigned short* __restrict__ wthi,
                         unsigned short* __restrict__ wtlo, int K) {
  int i = blockIdx.x * blockDim.x + threadIdx.x;
  if (i >= K * 256) return;
  int k = i >> 8, n = i & 255;
  float wv = W[(size_t)k * 256 + n];
  unsigned short hi = f2bf(wv);
  float r = wv - bf2f(hi);
  wthi[(size_t)n * K + k] = hi;
  wtlo[(size_t)n * K + k] = f2bf(r);
}

// x [N,126] fp32 -> X [N,128] bf16, zero-padded
__global__ void padx_kernel(const float* __restrict__ x, unsigned short* __restrict__ X, int N) {
  long long i = (long long)blockIdx.x * blockDim.x + threadIdx.x;
  if (i >= (long long)N * 128) return;
  int r = (int)(i >> 7), f = (int)(i & 127);
  X[i] = (f < F_IN) ? f2bf(x[(size_t)r * F_IN + f]) : (unsigned short)0;
}

// ---------------------------------------------------------------- SpMM (CSR, wave per row, bf16 in, bf16 out, fp32 accum)

__global__ __launch_bounds__(256) void spmm_kernel_128(
    const unsigned short* __restrict__ H, const int* __restrict__ rowstart,
    const int* __restrict__ col, const float* __restrict__ val,
    const float* __restrict__ dinv, unsigned short* __restrict__ G,
    float* __restrict__ svec, int N)
{
  int wave = threadIdx.x >> 6, lane = threadIdx.x & 63;
  int row = blockIdx.x * 4 + wave;
  if (row >= N) return;
  float dv = dinv[row];
  float self = dv * dv;
  unsigned int sv0 = *(const unsigned int*)(H + (size_t)row * 128 + lane * 2);
  float2 acc;
  acc.x = self * bf2f((unsigned short)(sv0 & 0xFFFF));
  acc.y = self * bf2f((unsigned short)(sv0 >> 16));
  float vsum = self;
  int e0 = rowstart[row], e1 = rowstart[row + 1];
  for (int e = e0; e < e1; ++e) {
    int sc = col[e];
    float v = val[e];
    unsigned int hv = *(const unsigned int*)(H + (size_t)sc * 128 + lane * 2);
    acc.x = fmaf(v, bf2f((unsigned short)(hv & 0xFFFF)), acc.x);
    acc.y = fmaf(v, bf2f((unsigned short)(hv >> 16)), acc.y);
    vsum += v;
  }
  unsigned int o = (unsigned int)f2bf(acc.x) | ((unsigned int)f2bf(acc.y) << 16);
  *(unsigned int*)(G + (size_t)row * 128 + lane * 2) = o;
  if (lane == 0) svec[row] = vsum;
}

__global__ __launch_bounds__(256) void spmm_kernel_256(
    const unsigned short* __restrict__ H, const int* __restrict__ rowstart,
    const int* __restrict__ col, const float* __restrict__ val,
    const float* __restrict__ dinv, unsigned short* __restrict__ G, int N)
{
  int wave = threadIdx.x >> 6, lane = threadIdx.x & 63;
  int row = blockIdx.x * 4 + wave;
  if (row >= N) return;
  float dv = dinv[row];
  float self = dv * dv;
  uint2 sv0 = *(const uint2*)(H + (size_t)row * 256 + lane * 4);
  float4 acc;
  acc.x = self * bf2f((unsigned short)(sv0.x & 0xFFFF));
  acc.y = self * bf2f((unsigned short)(sv0.x >> 16));
  acc.z = self * bf2f((unsigned short)(sv0.y & 0xFFFF));
  acc.w = self * bf2f((unsigned short)(sv0.y >> 16));
  int e0 = rowstart[row], e1 = rowstart[row + 1];
  for (int e = e0; e < e1; ++e) {
    int sc = col[e];
    float v = val[e];
    uint2 hv = *(const uint2*)(H + (size_t)sc * 256 + lane * 4);
    acc.x = fmaf(v, bf2f((unsigned short)(hv.x & 0xFFFF)), acc.x);
    acc.y = fmaf(v, bf2f((unsigned short)(hv.x >> 16)), acc.y);
    acc.z = fmaf(v, bf2f((unsigned short)(hv.y & 0xFFFF)), acc.z);
    acc.w = fmaf(v, bf2f((unsigned short)(hv.y >> 16)), acc.w);
  }
  uint2 o;
  o.x = (unsigned int)f2bf(acc.x) | ((unsigned int)f2bf(acc.y) << 16);
  o.y = (unsigned int)f2bf(acc.z) | ((unsigned int)f2bf(acc.w) << 16);
  *(uint2*)(G + (size_t)row * 256 + lane * 4) = o;
}

// ---------------------------------------------------------------- MFMA GEMM + bias + leaky-relu
// out[M,256] = act(A[M,K](bf16) @ (WtHi+WtLo)^T + bias + useS*s[i]*c[n]), bf16 out.
// Block 128x128 (4 waves 2x2, each 64x64 = 4x4 MFMA frags), K in steps of 32, no LDS.
// mfma_f32_16x16x32_bf16 layouts: A row=l&15, k=(l>>4)*8+j ; B col=l&15 (Wt row), same k ;
// C col=l&15, row=(l>>4)*4+reg.

__global__ __launch_bounds__(256) void gemm_mfma(
    const unsigned short* __restrict__ A, const unsigned short* __restrict__ WtHi,
    const unsigned short* __restrict__ WtLo, const float* __restrict__ bias,
    const float* __restrict__ s, const float* __restrict__ c,
    unsigned short* __restrict__ out, int M, int K, int useS)
{
  int wv = threadIdx.x >> 6, l = threadIdx.x & 63;
  int lr = l & 15, lg = l >> 4;
  int row0 = blockIdx.x * 128 + (wv >> 1) * 64;
  int col0 = blockIdx.y * 128 + (wv & 1) * 64;

  f32x4 acc[4][4];
  #pragma unroll
  for (int i = 0; i < 4; ++i)
    #pragma unroll
    for (int j = 0; j < 4; ++j)
      acc[i][j] = (f32x4){0.f, 0.f, 0.f, 0.f};

  for (int kc = 0; kc < K; kc += 32) {
    bf16x8 a[4], bh[4], bl[4];
    #pragma unroll
    for (int fi = 0; fi < 4; ++fi)
      a[fi] = *(const bf16x8*)(A + (size_t)(row0 + fi * 16 + lr) * K + kc + lg * 8);
    #pragma unroll
    for (int fj = 0; fj < 4; ++fj) {
      bh[fj] = *(const bf16x8*)(WtHi + (size_t)(col0 + fj * 16 + lr) * K + kc + lg * 8);
      bl[fj] = *(const bf16x8*)(WtLo + (size_t)(col0 + fj * 16 + lr) * K + kc + lg * 8);
    }
    #pragma unroll
    for (int fi = 0; fi < 4; ++fi)
      #pragma unroll
      for (int fj = 0; fj < 4; ++fj) {
        acc[fi][fj] = __builtin_amdgcn_mfma_f32_16x16x32_bf16(a[fi], bh[fj], acc[fi][fj], 0, 0, 0);
        acc[fi][fj] = __builtin_amdgcn_mfma_f32_16x16x32_bf16(a[fi], bl[fj], acc[fi][fj], 0, 0, 0);
      }
  }

  float bb[4], cv[4];
  #pragma unroll
  for (int fj = 0; fj < 4; ++fj) {
    int colj = col0 + fj * 16 + lr;
    bb[fj] = bias[colj];
    cv[fj] = useS ? c[colj] : 0.0f;
  }
  #pragma unroll
  for (int fi = 0; fi < 4; ++fi) {
    #pragma unroll
    for (int r = 0; r < 4; ++r) {
      int row = row0 + fi * 16 + lg * 4 + r;
      if (row < M) {
        float sv = useS ? s[row] : 0.0f;
        #pragma unroll
        for (int fj = 0; fj < 4; ++fj) {
          float v = acc[fi][fj][r] + bb[fj] + sv * cv[fj];
          v = v > 0.0f ? v : 0.01f * v;
          out[(size_t)row * 256 + col0 + fj * 16 + lr] = f2bf(v);
        }
      }
    }
  }
}

// ---------------------------------------------------------------- pooling + head

__global__ void colsum_kernel(const unsigned short* __restrict__ H, float* __restrict__ pooled, int N) {
  int t = threadIdx.x;
  float acc = 0.f;
  for (int r = blockIdx.x; r < N; r += gridDim.x)
    acc += bf2f(H[(size_t)r * 256 + t]);
  atomicAdd(&pooled[t], acc);
}

__global__ void final_kernel(const float* __restrict__ pooled, const float* __restrict__ Wlin,
                             const float* __restrict__ blin, float* __restrict__ out, float invN) {
  __shared__ float sd[256];
  int t = threadIdx.x;
  sd[t] = pooled[t] * invN * Wlin[t];
  __syncthreads();
  for (int off = 128; off > 0; off >>= 1) {
    if (t < off) sd[t] += sd[t + off];
    __syncthreads();
  }
  if (t == 0) out[0] = sd[0] + blin[0];
}

// ---------------------------------------------------------------- launch

extern "C" void kernel_launch(void* const* d_in, const int* in_sizes, int n_in,
                              void* d_out, int out_size, void* d_ws, size_t ws_size,
                              hipStream_t stream) {
  const float* x    = (const float*)d_in[0];
  const int*   ei   = (const int*)d_in[1];     // int32 on the wire
  const float* u    = (const float*)d_in[2];
  const float* w    = (const float*)d_in[3];
  const float* W1   = (const float*)d_in[4];  const float* b1 = (const float*)d_in[5];
  const float* W2   = (const float*)d_in[6];  const float* b2 = (const float*)d_in[7];
  const float* W3   = (const float*)d_in[8];  const float* b3 = (const float*)d_in[9];
  const float* W4   = (const float*)d_in[10]; const float* b4 = (const float*)d_in[11];
  const float* W5   = (const float*)d_in[12]; const float* b5 = (const float*)d_in[13];
  const float* Wlin = (const float*)d_in[14]; const float* blin = (const float*)d_in[15];

  int N = in_sizes[0] / F_IN;
  int E = in_sizes[1] / 2;
  int Npad = (N + 127) & ~127;
  const int* srcp = ei;
  const int* dstp = ei + E;

  char* p = (char*)d_ws;
  auto alloc = [&](size_t bytes) { char* r = p; p += (bytes + 255) & ~(size_t)255; return r; };
  unsigned short* bufH = (unsigned short*)alloc((size_t)Npad * 256 * 2);  // bf16 hidden
  unsigned short* bufG = (unsigned short*)alloc((size_t)Npad * 256 * 2);  // bf16 aggregate
  int*   colA     = (int*)alloc((size_t)E * 4);
  float* valA     = (float*)alloc((size_t)E * 4);
  int*   cnt      = (int*)alloc((size_t)N * 4);
  float* dinv     = (float*)alloc((size_t)N * 4);
  int*   rowstart = (int*)alloc((size_t)(N + 1) * 4);
  int*   cursor   = (int*)alloc((size_t)N * 4);
  float* svec     = (float*)alloc((size_t)N * 4);
  float* cvec     = (float*)alloc(256 * 4);
  int*   blocksum = (int*)alloc(128 * 4);
  int*   blockoff = (int*)alloc(128 * 4);
  float* pooled   = (float*)alloc(256 * 4);
  // transposed hi/lo weight planes: [256 cols][K]
  unsigned short* wt1h = (unsigned short*)alloc(256 * 128 * 2);
  unsigned short* wt1l = (unsigned short*)alloc(256 * 128 * 2);
  unsigned short* wth[4]; unsigned short* wtl[4];
  for (int i = 0; i < 4; ++i) {
    wth[i] = (unsigned short*)alloc(256 * 256 * 2);
    wtl[i] = (unsigned short*)alloc(256 * 256 * 2);
  }

  hipMemsetAsync(cnt, 0, (size_t)N * 4, stream);
  hipMemsetAsync(pooled, 0, 256 * 4, stream);
  // zero A-pad rows (read by gemm fragment loads): 128-wide and 256-wide regions of bufG
  hipMemsetAsync(bufG + (size_t)N * 128, 0, (size_t)(Npad - N) * 128 * 2, stream);
  hipMemsetAsync(bufG + (size_t)N * 256, 0, (size_t)(Npad - N) * 256 * 2, stream);

  const int tpb = 256;
  hist_kernel<<<(E + tpb - 1) / tpb, tpb, 0, stream>>>(dstp, E, cnt);
  dinv_kernel<<<(N + tpb - 1) / tpb, tpb, 0, stream>>>(cnt, dinv, N);
  int nblk = (N + 1023) / 1024;
  scan_local<<<nblk, 1024, 0, stream>>>(cnt, rowstart, blocksum, N);
  scan_blk<<<1, 128, 0, stream>>>(blocksum, blockoff, nblk);
  scan_add<<<(N + tpb - 1) / tpb, tpb, 0, stream>>>(rowstart, blockoff, cursor, N, E);
  fill_csr<<<(E + tpb - 1) / tpb, tpb, 0, stream>>>(srcp, dstp, dinv, cursor, colA, valA, E);
  c_kernel<<<1, 256, 0, stream>>>(W1, u, w, cvec);

  wt_split<<<(128 * 256 + tpb - 1) / tpb, tpb, 0, stream>>>(W1, wt1h, wt1l, 128);
  const float* Ws[4] = {W2, W3, W4, W5};
  const float* bs[4] = {b2, b3, b4, b5};
  for (int i = 0; i < 4; ++i)
    wt_split<<<(256 * 256 + tpb - 1) / tpb, tpb, 0, stream>>>(Ws[i], wth[i], wtl[i], 256);

  long long nx = (long long)N * 128;
  padx_kernel<<<(int)((nx + tpb - 1) / tpb), tpb, 0, stream>>>(x, bufH, N);

  dim3 ggrid(Npad / 128, 2);
  // layer 1: aggregate at width 128 (bf16), transform 128->256 with s*c epilogue
  spmm_kernel_128<<<(N + 3) / 4, 256, 0, stream>>>(bufH, rowstart, colA, valA, dinv, bufG, svec, N);
  gemm_mfma<<<ggrid, 256, 0, stream>>>(bufG, wt1h, wt1l, b1, svec, cvec, bufH, N, 128, 1);

  for (int l = 0; l < 4; ++l) {
    spmm_kernel_256<<<(N + 3) / 4, 256, 0, stream>>>(bufH, rowstart, colA, valA, dinv, bufG, N);
    gemm_mfma<<<ggrid, 256, 0, stream>>>(bufG, wth[l], wtl[l], bs[l], svec, cvec, bufH, N, 256, 0);
  }

  colsum_kernel<<<2048, 256, 0, stream>>>(bufH, pooled, N);
  final_kernel<<<1, 256, 0, stream>>>(pooled, Wlin, blin, (float*)d_out, 1.0f / (float)N);
}

// Round 7
// 1324.517 us; speedup vs baseline: 1.7373x; 1.2331x over previous
//
#include <hip/hip_runtime.h>
#include <hip/hip_bf16.h>
#include <cstdint>
#include <cstddef>

#define F_IN 126
#define HID 256

typedef __attribute__((ext_vector_type(8))) short bf16x8;
typedef __attribute__((ext_vector_type(4))) float f32x4;

// bf16 storage helpers (arithmetic stays fp32)
__device__ __forceinline__ float bf2f(unsigned short u) {
  union { unsigned int i; float f; } v; v.i = ((unsigned int)u) << 16; return v.f;
}
__device__ __forceinline__ unsigned short f2bf(float x) {
  union { float f; unsigned int i; } v; v.f = x;
  unsigned int b = v.i + 0x7FFFu + ((v.i >> 16) & 1u);  // round-to-nearest-even
  return (unsigned short)(b >> 16);
}
__device__ __forceinline__ float asf(unsigned int u) {
  union { unsigned int i; float f; } v; v.i = u; return v.f;
}

// ---------------------------------------------------------------- graph prep

__global__ void hist_kernel(const int* __restrict__ dst, int E, int* __restrict__ cnt) {
  int e = blockIdx.x * blockDim.x + threadIdx.x;
  if (e < E) atomicAdd(&cnt[dst[e]], 1);
}

__global__ void dinv_kernel(const int* __restrict__ cnt, float* __restrict__ dinv, int N) {
  int i = blockIdx.x * blockDim.x + threadIdx.x;
  if (i < N) dinv[i] = rsqrtf((float)(cnt[i] + 1));  // self-loop => deg >= 1
}

__global__ void scan_local(const int* __restrict__ cnt, int* __restrict__ rowstart,
                           int* __restrict__ blocksum, int N) {
  __shared__ int sd[1024];
  int t = threadIdx.x;
  int gi = blockIdx.x * 1024 + t;
  int v = (gi < N) ? cnt[gi] : 0;
  sd[t] = v;
  __syncthreads();
  for (int off = 1; off < 1024; off <<= 1) {
    int add = (t >= off) ? sd[t - off] : 0;
    __syncthreads();
    sd[t] += add;
    __syncthreads();
  }
  if (gi < N) rowstart[gi] = sd[t] - v;
  if (t == 1023) blocksum[blockIdx.x] = sd[1023];
}

__global__ void scan_blk(const int* __restrict__ blocksum, int* __restrict__ blockoff, int nblk) {
  __shared__ int sd[128];
  int t = threadIdx.x;
  int v = (t < nblk) ? blocksum[t] : 0;
  sd[t] = v;
  __syncthreads();
  for (int off = 1; off < 128; off <<= 1) {
    int add = (t >= off) ? sd[t - off] : 0;
    __syncthreads();
    sd[t] += add;
    __syncthreads();
  }
  if (t < nblk) blockoff[t] = sd[t] - v;
}

__global__ void scan_add(int* __restrict__ rowstart, const int* __restrict__ blockoff,
                         int* __restrict__ cursor, int N, int E) {
  int i = blockIdx.x * blockDim.x + threadIdx.x;
  if (i < N) {
    int r = rowstart[i] + blockoff[i >> 10];
    rowstart[i] = r;
    cursor[i] = r;
  }
  if (i == 0) rowstart[N] = E;
}

// edges: interleaved (col, val-bits) pairs, one 8B load per edge in SpMM
__global__ void fill_csr(const int* __restrict__ srcp, const int* __restrict__ dstp,
                         const float* __restrict__ dinv, int* __restrict__ cursor,
                         uint2* __restrict__ edges, int E) {
  int e = blockIdx.x * blockDim.x + threadIdx.x;
  if (e >= E) return;
  int s = srcp[e];
  int d = dstp[e];
  int pos = atomicAdd(&cursor[d], 1);
  float v = dinv[s] * dinv[d];
  union { float f; unsigned int i; } vv; vv.f = v;
  edges[pos] = make_uint2((unsigned int)s, vv.i);
}

// c[n] = u*W1[126,n] + w*W1[127,n]
__global__ void c_kernel(const float* __restrict__ W1, const float* __restrict__ up,
                         const float* __restrict__ wp, float* __restrict__ c) {
  int n = threadIdx.x;
  c[n] = up[0] * W1[126 * 256 + n] + wp[0] * W1[127 * 256 + n];
}

// W [K,256] fp32 -> WtHi/WtLo [256,K] bf16 (transposed, hi + residual-lo split)
__global__ void wt_split(const float* __restrict__ W, unsigned short* __restrict__ wthi,
                         unsigned short* __restrict__ wtlo, int K) {
  int i = blockIdx.x * blockDim.x + threadIdx.x;
  if (i >= K * 256) return;
  int k = i >> 8, n = i & 255;
  float wv = W[(size_t)k * 256 + n];
  unsigned short hi = f2bf(wv);
  float r = wv - bf2f(hi);
  wthi[(size_t)n * K + k] = hi;
  wtlo[(size_t)n * K + k] = f2bf(r);
}

// x [N,126] fp32 -> X [N,128] bf16, zero-padded
__global__ void padx_kernel(const float* __restrict__ x, unsigned short* __restrict__ X, int N) {
  long long i = (long long)blockIdx.x * blockDim.x + threadIdx.x;
  if (i >= (long long)N * 128) return;
  int r = (int)(i >> 7), f = (int)(i & 127);
  X[i] = (f < F_IN) ? f2bf(x[(size_t)r * F_IN + f]) : (unsigned short)0;
}

// ---------------------------------------------------------------- SpMM (CSR, wave per row, bf16 in, bf16 out, fp32 accum)
// 4x unrolled edge loop: 4 edge-pair loads + 4 row gathers in flight per wave.

__global__ __launch_bounds__(256) void spmm_kernel_128(
    const unsigned short* __restrict__ H, const int* __restrict__ rowstart,
    const uint2* __restrict__ edges, const float* __restrict__ dinv,
    unsigned short* __restrict__ G, float* __restrict__ svec, int N)
{
  int wave = threadIdx.x >> 6, lane = threadIdx.x & 63;
  int row = blockIdx.x * 4 + wave;
  if (row >= N) return;
  float dv = dinv[row];
  float self = dv * dv;
  unsigned int sv0 = *(const unsigned int*)(H + (size_t)row * 128 + lane * 2);
  float2 acc;
  acc.x = self * bf2f((unsigned short)(sv0 & 0xFFFF));
  acc.y = self * bf2f((unsigned short)(sv0 >> 16));
  float vsum = self;
  int e0 = rowstart[row], e1 = rowstart[row + 1];
  int e = e0;
  for (; e + 4 <= e1; e += 4) {
    uint2 p0 = edges[e], p1 = edges[e + 1], p2 = edges[e + 2], p3 = edges[e + 3];
    unsigned int h0 = *(const unsigned int*)(H + (size_t)p0.x * 128 + lane * 2);
    unsigned int h1 = *(const unsigned int*)(H + (size_t)p1.x * 128 + lane * 2);
    unsigned int h2 = *(const unsigned int*)(H + (size_t)p2.x * 128 + lane * 2);
    unsigned int h3 = *(const unsigned int*)(H + (size_t)p3.x * 128 + lane * 2);
    float v0 = asf(p0.y), v1 = asf(p1.y), v2 = asf(p2.y), v3 = asf(p3.y);
    acc.x = fmaf(v0, bf2f((unsigned short)(h0 & 0xFFFF)), acc.x);
    acc.y = fmaf(v0, bf2f((unsigned short)(h0 >> 16)), acc.y);
    acc.x = fmaf(v1, bf2f((unsigned short)(h1 & 0xFFFF)), acc.x);
    acc.y = fmaf(v1, bf2f((unsigned short)(h1 >> 16)), acc.y);
    acc.x = fmaf(v2, bf2f((unsigned short)(h2 & 0xFFFF)), acc.x);
    acc.y = fmaf(v2, bf2f((unsigned short)(h2 >> 16)), acc.y);
    acc.x = fmaf(v3, bf2f((unsigned short)(h3 & 0xFFFF)), acc.x);
    acc.y = fmaf(v3, bf2f((unsigned short)(h3 >> 16)), acc.y);
    vsum += v0 + v1 + v2 + v3;
  }
  for (; e < e1; ++e) {
    uint2 p = edges[e];
    float v = asf(p.y);
    unsigned int hv = *(const unsigned int*)(H + (size_t)p.x * 128 + lane * 2);
    acc.x = fmaf(v, bf2f((unsigned short)(hv & 0xFFFF)), acc.x);
    acc.y = fmaf(v, bf2f((unsigned short)(hv >> 16)), acc.y);
    vsum += v;
  }
  unsigned int o = (unsigned int)f2bf(acc.x) | ((unsigned int)f2bf(acc.y) << 16);
  *(unsigned int*)(G + (size_t)row * 128 + lane * 2) = o;
  if (lane == 0) svec[row] = vsum;
}

__global__ __launch_bounds__(256) void spmm_kernel_256(
    const unsigned short* __restrict__ H, const int* __restrict__ rowstart,
    const uint2* __restrict__ edges, const float* __restrict__ dinv,
    unsigned short* __restrict__ G, int N)
{
  int wave = threadIdx.x >> 6, lane = threadIdx.x & 63;
  int row = blockIdx.x * 4 + wave;
  if (row >= N) return;
  float dv = dinv[row];
  float self = dv * dv;
  uint2 sv0 = *(const uint2*)(H + (size_t)row * 256 + lane * 4);
  float4 acc;
  acc.x = self * bf2f((unsigned short)(sv0.x & 0xFFFF));
  acc.y = self * bf2f((unsigned short)(sv0.x >> 16));
  acc.z = self * bf2f((unsigned short)(sv0.y & 0xFFFF));
  acc.w = self * bf2f((unsigned short)(sv0.y >> 16));
  int e0 = rowstart[row], e1 = rowstart[row + 1];
  int e = e0;
  for (; e + 4 <= e1; e += 4) {
    uint2 p0 = edges[e], p1 = edges[e + 1], p2 = edges[e + 2], p3 = edges[e + 3];
    uint2 h0 = *(const uint2*)(H + (size_t)p0.x * 256 + lane * 4);
    uint2 h1 = *(const uint2*)(H + (size_t)p1.x * 256 + lane * 4);
    uint2 h2 = *(const uint2*)(H + (size_t)p2.x * 256 + lane * 4);
    uint2 h3 = *(const uint2*)(H + (size_t)p3.x * 256 + lane * 4);
    float v0 = asf(p0.y), v1 = asf(p1.y), v2 = asf(p2.y), v3 = asf(p3.y);
    acc.x = fmaf(v0, bf2f((unsigned short)(h0.x & 0xFFFF)), acc.x);
    acc.y = fmaf(v0, bf2f((unsigned short)(h0.x >> 16)), acc.y);
    acc.z = fmaf(v0, bf2f((unsigned short)(h0.y & 0xFFFF)), acc.z);
    acc.w = fmaf(v0, bf2f((unsigned short)(h0.y >> 16)), acc.w);
    acc.x = fmaf(v1, bf2f((unsigned short)(h1.x & 0xFFFF)), acc.x);
    acc.y = fmaf(v1, bf2f((unsigned short)(h1.x >> 16)), acc.y);
    acc.z = fmaf(v1, bf2f((unsigned short)(h1.y & 0xFFFF)), acc.z);
    acc.w = fmaf(v1, bf2f((unsigned short)(h1.y >> 16)), acc.w);
    acc.x = fmaf(v2, bf2f((unsigned short)(h2.x & 0xFFFF)), acc.x);
    acc.y = fmaf(v2, bf2f((unsigned short)(h2.x >> 16)), acc.y);
    acc.z = fmaf(v2, bf2f((unsigned short)(h2.y & 0xFFFF)), acc.z);
    acc.w = fmaf(v2, bf2f((unsigned short)(h2.y >> 16)), acc.w);
    acc.x = fmaf(v3, bf2f((unsigned short)(h3.x & 0xFFFF)), acc.x);
    acc.y = fmaf(v3, bf2f((unsigned short)(h3.x >> 16)), acc.y);
    acc.z = fmaf(v3, bf2f((unsigned short)(h3.y & 0xFFFF)), acc.z);
    acc.w = fmaf(v3, bf2f((unsigned short)(h3.y >> 16)), acc.w);
  }
  for (; e < e1; ++e) {
    uint2 p = edges[e];
    float v = asf(p.y);
    uint2 hv = *(const uint2*)(H + (size_t)p.x * 256 + lane * 4);
    acc.x = fmaf(v, bf2f((unsigned short)(hv.x & 0xFFFF)), acc.x);
    acc.y = fmaf(v, bf2f((unsigned short)(hv.x >> 16)), acc.y);
    acc.z = fmaf(v, bf2f((unsigned short)(hv.y & 0xFFFF)), acc.z);
    acc.w = fmaf(v, bf2f((unsigned short)(hv.y >> 16)), acc.w);
  }
  uint2 o;
  o.x = (unsigned int)f2bf(acc.x) | ((unsigned int)f2bf(acc.y) << 16);
  o.y = (unsigned int)f2bf(acc.z) | ((unsigned int)f2bf(acc.w) << 16);
  *(uint2*)(G + (size_t)row * 256 + lane * 4) = o;
}

// ---------------------------------------------------------------- MFMA GEMM + bias + leaky-relu
// out[M,256] = act(A[M,K](bf16) @ (WtHi+WtLo)^T + bias + useS*s[i]*c[n]), bf16 out.

__global__ __launch_bounds__(256) void gemm_mfma(
    const unsigned short* __restrict__ A, const unsigned short* __restrict__ WtHi,
    const unsigned short* __restrict__ WtLo, const float* __restrict__ bias,
    const float* __restrict__ s, const float* __restrict__ c,
    unsigned short* __restrict__ out, int M, int K, int useS)
{
  int wv = threadIdx.x >> 6, l = threadIdx.x & 63;
  int lr = l & 15, lg = l >> 4;
  int row0 = blockIdx.x * 128 + (wv >> 1) * 64;
  int col0 = blockIdx.y * 128 + (wv & 1) * 64;

  f32x4 acc[4][4];
  #pragma unroll
  for (int i = 0; i < 4; ++i)
    #pragma unroll
    for (int j = 0; j < 4; ++j)
      acc[i][j] = (f32x4){0.f, 0.f, 0.f, 0.f};

  for (int kc = 0; kc < K; kc += 32) {
    bf16x8 a[4], bh[4], bl[4];
    #pragma unroll
    for (int fi = 0; fi < 4; ++fi)
      a[fi] = *(const bf16x8*)(A + (size_t)(row0 + fi * 16 + lr) * K + kc + lg * 8);
    #pragma unroll
    for (int fj = 0; fj < 4; ++fj) {
      bh[fj] = *(const bf16x8*)(WtHi + (size_t)(col0 + fj * 16 + lr) * K + kc + lg * 8);
      bl[fj] = *(const bf16x8*)(WtLo + (size_t)(col0 + fj * 16 + lr) * K + kc + lg * 8);
    }
    #pragma unroll
    for (int fi = 0; fi < 4; ++fi)
      #pragma unroll
      for (int fj = 0; fj < 4; ++fj) {
        acc[fi][fj] = __builtin_amdgcn_mfma_f32_16x16x32_bf16(a[fi], bh[fj], acc[fi][fj], 0, 0, 0);
        acc[fi][fj] = __builtin_amdgcn_mfma_f32_16x16x32_bf16(a[fi], bl[fj], acc[fi][fj], 0, 0, 0);
      }
  }

  float bb[4], cv[4];
  #pragma unroll
  for (int fj = 0; fj < 4; ++fj) {
    int colj = col0 + fj * 16 + lr;
    bb[fj] = bias[colj];
    cv[fj] = useS ? c[colj] : 0.0f;
  }
  #pragma unroll
  for (int fi = 0; fi < 4; ++fi) {
    #pragma unroll
    for (int r = 0; r < 4; ++r) {
      int row = row0 + fi * 16 + lg * 4 + r;
      if (row < M) {
        float sv = useS ? s[row] : 0.0f;
        #pragma unroll
        for (int fj = 0; fj < 4; ++fj) {
          float v = acc[fi][fj][r] + bb[fj] + sv * cv[fj];
          v = v > 0.0f ? v : 0.01f * v;
          out[(size_t)row * 256 + col0 + fj * 16 + lr] = f2bf(v);
        }
      }
    }
  }
}

// ---------------------------------------------------------------- pooling + head

__global__ void colsum_kernel(const unsigned short* __restrict__ H, float* __restrict__ pooled, int N) {
  int t = threadIdx.x;
  float acc = 0.f;
  for (int r = blockIdx.x; r < N; r += gridDim.x)
    acc += bf2f(H[(size_t)r * 256 + t]);
  atomicAdd(&pooled[t], acc);
}

__global__ void final_kernel(const float* __restrict__ pooled, const float* __restrict__ Wlin,
                             const float* __restrict__ blin, float* __restrict__ out, float invN) {
  __shared__ float sd[256];
  int t = threadIdx.x;
  sd[t] = pooled[t] * invN * Wlin[t];
  __syncthreads();
  for (int off = 128; off > 0; off >>= 1) {
    if (t < off) sd[t] += sd[t + off];
    __syncthreads();
  }
  if (t == 0) out[0] = sd[0] + blin[0];
}

// ---------------------------------------------------------------- launch

extern "C" void kernel_launch(void* const* d_in, const int* in_sizes, int n_in,
                              void* d_out, int out_size, void* d_ws, size_t ws_size,
                              hipStream_t stream) {
  const float* x    = (const float*)d_in[0];
  const int*   ei   = (const int*)d_in[1];     // int32 on the wire
  const float* u    = (const float*)d_in[2];
  const float* w    = (const float*)d_in[3];
  const float* W1   = (const float*)d_in[4];  const float* b1 = (const float*)d_in[5];
  const float* W2   = (const float*)d_in[6];  const float* b2 = (const float*)d_in[7];
  const float* W3   = (const float*)d_in[8];  const float* b3 = (const float*)d_in[9];
  const float* W4   = (const float*)d_in[10]; const float* b4 = (const float*)d_in[11];
  const float* W5   = (const float*)d_in[12]; const float* b5 = (const float*)d_in[13];
  const float* Wlin = (const float*)d_in[14]; const float* blin = (const float*)d_in[15];

  int N = in_sizes[0] / F_IN;
  int E = in_sizes[1] / 2;
  int Npad = (N + 127) & ~127;
  const int* srcp = ei;
  const int* dstp = ei + E;

  char* p = (char*)d_ws;
  auto alloc = [&](size_t bytes) { char* r = p; p += (bytes + 255) & ~(size_t)255; return r; };
  unsigned short* bufH = (unsigned short*)alloc((size_t)Npad * 256 * 2);  // bf16 hidden
  unsigned short* bufG = (unsigned short*)alloc((size_t)Npad * 256 * 2);  // bf16 aggregate
  uint2* edges    = (uint2*)alloc((size_t)E * 8);                         // (col, val) pairs
  int*   cnt      = (int*)alloc((size_t)N * 4);
  float* dinv     = (float*)alloc((size_t)N * 4);
  int*   rowstart = (int*)alloc((size_t)(N + 1) * 4);
  int*   cursor   = (int*)alloc((size_t)N * 4);
  float* svec     = (float*)alloc((size_t)N * 4);
  float* cvec     = (float*)alloc(256 * 4);
  int*   blocksum = (int*)alloc(128 * 4);
  int*   blockoff = (int*)alloc(128 * 4);
  float* pooled   = (float*)alloc(256 * 4);
  // transposed hi/lo weight planes: [256 cols][K]
  unsigned short* wt1h = (unsigned short*)alloc(256 * 128 * 2);
  unsigned short* wt1l = (unsigned short*)alloc(256 * 128 * 2);
  unsigned short* wth[4]; unsigned short* wtl[4];
  for (int i = 0; i < 4; ++i) {
    wth[i] = (unsigned short*)alloc(256 * 256 * 2);
    wtl[i] = (unsigned short*)alloc(256 * 256 * 2);
  }

  hipMemsetAsync(cnt, 0, (size_t)N * 4, stream);
  hipMemsetAsync(pooled, 0, 256 * 4, stream);
  // zero A-pad rows (read by gemm fragment loads): 128-wide and 256-wide regions of bufG
  hipMemsetAsync(bufG + (size_t)N * 128, 0, (size_t)(Npad - N) * 128 * 2, stream);
  hipMemsetAsync(bufG + (size_t)N * 256, 0, (size_t)(Npad - N) * 256 * 2, stream);

  const int tpb = 256;
  hist_kernel<<<(E + tpb - 1) / tpb, tpb, 0, stream>>>(dstp, E, cnt);
  dinv_kernel<<<(N + tpb - 1) / tpb, tpb, 0, stream>>>(cnt, dinv, N);
  int nblk = (N + 1023) / 1024;
  scan_local<<<nblk, 1024, 0, stream>>>(cnt, rowstart, blocksum, N);
  scan_blk<<<1, 128, 0, stream>>>(blocksum, blockoff, nblk);
  scan_add<<<(N + tpb - 1) / tpb, tpb, 0, stream>>>(rowstart, blockoff, cursor, N, E);
  fill_csr<<<(E + tpb - 1) / tpb, tpb, 0, stream>>>(srcp, dstp, dinv, cursor, edges, E);
  c_kernel<<<1, 256, 0, stream>>>(W1, u, w, cvec);

  wt_split<<<(128 * 256 + tpb - 1) / tpb, tpb, 0, stream>>>(W1, wt1h, wt1l, 128);
  const float* Ws[4] = {W2, W3, W4, W5};
  const float* bs[4] = {b2, b3, b4, b5};
  for (int i = 0; i < 4; ++i)
    wt_split<<<(256 * 256 + tpb - 1) / tpb, tpb, 0, stream>>>(Ws[i], wth[i], wtl[i], 256);

  long long nx = (long long)N * 128;
  padx_kernel<<<(int)((nx + tpb - 1) / tpb), tpb, 0, stream>>>(x, bufH, N);

  dim3 ggrid(Npad / 128, 2);
  // layer 1: aggregate at width 128 (bf16), transform 128->256 with s*c epilogue
  spmm_kernel_128<<<(N + 3) / 4, 256, 0, stream>>>(bufH, rowstart, edges, dinv, bufG, svec, N);
  gemm_mfma<<<ggrid, 256, 0, stream>>>(bufG, wt1h, wt1l, b1, svec, cvec, bufH, N, 128, 1);

  for (int l = 0; l < 4; ++l) {
    spmm_kernel_256<<<(N + 3) / 4, 256, 0, stream>>>(bufH, rowstart, edges, dinv, bufG, N);
    gemm_mfma<<<ggrid, 256, 0, stream>>>(bufG, wth[l], wtl[l], bs[l], svec, cvec, bufH, N, 256, 0);
  }

  colsum_kernel<<<2048, 256, 0, stream>>>(bufH, pooled, N);
  final_kernel<<<1, 256, 0, stream>>>(pooled, Wlin, blin, (float*)d_out, 1.0f / (float)N);
}

// Round 10
// 1322.101 us; speedup vs baseline: 1.7405x; 1.0018x over previous
//
#include <hip/hip_runtime.h>
#include <hip/hip_bf16.h>
#include <cstdint>
#include <cstddef>

#define F_IN 126
#define HID 256

typedef __attribute__((ext_vector_type(8))) short bf16x8;
typedef __attribute__((ext_vector_type(4))) float f32x4;

// bf16 storage helpers (arithmetic stays fp32)
__device__ __forceinline__ float bf2f(unsigned short u) {
  union { unsigned int i; float f; } v; v.i = ((unsigned int)u) << 16; return v.f;
}
__device__ __forceinline__ unsigned short f2bf(float x) {
  union { float f; unsigned int i; } v; v.f = x;
  unsigned int b = v.i + 0x7FFFu + ((v.i >> 16) & 1u);  // round-to-nearest-even
  return (unsigned short)(b >> 16);
}
__device__ __forceinline__ float asf(unsigned int u) {
  union { unsigned int i; float f; } v; v.i = u; return v.f;
}

// ---------------------------------------------------------------- graph prep

__global__ void hist_kernel(const int* __restrict__ dst, int E, int* __restrict__ cnt) {
  int e = blockIdx.x * blockDim.x + threadIdx.x;
  if (e < E) atomicAdd(&cnt[dst[e]], 1);
}

__global__ void dinv_kernel(const int* __restrict__ cnt, float* __restrict__ dinv, int N) {
  int i = blockIdx.x * blockDim.x + threadIdx.x;
  if (i < N) dinv[i] = rsqrtf((float)(cnt[i] + 1));  // self-loop => deg >= 1
}

__global__ void scan_local(const int* __restrict__ cnt, int* __restrict__ rowstart,
                           int* __restrict__ blocksum, int N) {
  __shared__ int sd[1024];
  int t = threadIdx.x;
  int gi = blockIdx.x * 1024 + t;
  int v = (gi < N) ? cnt[gi] : 0;
  sd[t] = v;
  __syncthreads();
  for (int off = 1; off < 1024; off <<= 1) {
    int add = (t >= off) ? sd[t - off] : 0;
    __syncthreads();
    sd[t] += add;
    __syncthreads();
  }
  if (gi < N) rowstart[gi] = sd[t] - v;
  if (t == 1023) blocksum[blockIdx.x] = sd[1023];
}

__global__ void scan_blk(const int* __restrict__ blocksum, int* __restrict__ blockoff, int nblk) {
  __shared__ int sd[128];
  int t = threadIdx.x;
  int v = (t < nblk) ? blocksum[t] : 0;
  sd[t] = v;
  __syncthreads();
  for (int off = 1; off < 128; off <<= 1) {
    int add = (t >= off) ? sd[t - off] : 0;
    __syncthreads();
    sd[t] += add;
    __syncthreads();
  }
  if (t < nblk) blockoff[t] = sd[t] - v;
}

__global__ void scan_add(int* __restrict__ rowstart, const int* __restrict__ blockoff,
                         int* __restrict__ cursor, int N, int E) {
  int i = blockIdx.x * blockDim.x + threadIdx.x;
  if (i < N) {
    int r = rowstart[i] + blockoff[i >> 10];
    rowstart[i] = r;
    cursor[i] = r;
  }
  if (i == 0) rowstart[N] = E;
}

// edges: interleaved (col, val-bits) pairs, one 8B load per edge in SpMM
__global__ void fill_csr(const int* __restrict__ srcp, const int* __restrict__ dstp,
                         const float* __restrict__ dinv, int* __restrict__ cursor,
                         uint2* __restrict__ edges, int E) {
  int e = blockIdx.x * blockDim.x + threadIdx.x;
  if (e >= E) return;
  int s = srcp[e];
  int d = dstp[e];
  int pos = atomicAdd(&cursor[d], 1);
  float v = dinv[s] * dinv[d];
  union { float f; unsigned int i; } vv; vv.f = v;
  edges[pos] = make_uint2((unsigned int)s, vv.i);
}

// c[n] = u*W1[126,n] + w*W1[127,n]
__global__ void c_kernel(const float* __restrict__ W1, const float* __restrict__ up,
                         const float* __restrict__ wp, float* __restrict__ c) {
  int n = threadIdx.x;
  c[n] = up[0] * W1[126 * 256 + n] + wp[0] * W1[127 * 256 + n];
}

// W [K,256] fp32 -> WtHi/WtLo [256,K] bf16 (transposed, hi + residual-lo split)
__global__ void wt_split(const float* __restrict__ W, unsigned short* __restrict__ wthi,
                         unsigned short* __restrict__ wtlo, int K) {
  int i = blockIdx.x * blockDim.x + threadIdx.x;
  if (i >= K * 256) return;
  int k = i >> 8, n = i & 255;
  float wv = W[(size_t)k * 256 + n];
  unsigned short hi = f2bf(wv);
  float r = wv - bf2f(hi);
  wthi[(size_t)n * K + k] = hi;
  wtlo[(size_t)n * K + k] = f2bf(r);
}

// x [N,126] fp32 -> X [N,128] bf16, zero-padded
__global__ void padx_kernel(const float* __restrict__ x, unsigned short* __restrict__ X, int N) {
  long long i = (long long)blockIdx.x * blockDim.x + threadIdx.x;
  if (i >= (long long)N * 128) return;
  int r = (int)(i >> 7), f = (int)(i & 127);
  X[i] = (f < F_IN) ? f2bf(x[(size_t)r * F_IN + f]) : (unsigned short)0;
}

// ---------------------------------------------------------------- SpMM (CSR, wave per row, bf16 in, bf16 out, fp32 accum)
// 8x unrolled edge loop: 8 edge-pair loads + 8 row gathers in flight per wave.

__global__ __launch_bounds__(256) void spmm_kernel_128(
    const unsigned short* __restrict__ H, const int* __restrict__ rowstart,
    const uint2* __restrict__ edges, const float* __restrict__ dinv,
    unsigned short* __restrict__ G, float* __restrict__ svec, int N)
{
  int wave = threadIdx.x >> 6, lane = threadIdx.x & 63;
  int row = blockIdx.x * 4 + wave;
  if (row >= N) return;
  const unsigned short* Hl = H + lane * 2;
  float dv = dinv[row];
  float self = dv * dv;
  unsigned int sv0 = *(const unsigned int*)(Hl + (size_t)row * 128);
  float2 acc;
  acc.x = self * bf2f((unsigned short)(sv0 & 0xFFFF));
  acc.y = self * bf2f((unsigned short)(sv0 >> 16));
  float vsum = self;
  int e0 = rowstart[row], e1 = rowstart[row + 1];
  int e = e0;
  for (; e + 8 <= e1; e += 8) {
    unsigned int h[8]; float v[8];
    #pragma unroll
    for (int q = 0; q < 8; ++q) {
      uint2 pq = edges[e + q];
      v[q] = asf(pq.y);
      h[q] = *(const unsigned int*)(Hl + (size_t)pq.x * 128);
    }
    #pragma unroll
    for (int q = 0; q < 8; ++q) {
      acc.x = fmaf(v[q], bf2f((unsigned short)(h[q] & 0xFFFF)), acc.x);
      acc.y = fmaf(v[q], bf2f((unsigned short)(h[q] >> 16)), acc.y);
      vsum += v[q];
    }
  }
  for (; e < e1; ++e) {
    uint2 p = edges[e];
    float v = asf(p.y);
    unsigned int hv = *(const unsigned int*)(Hl + (size_t)p.x * 128);
    acc.x = fmaf(v, bf2f((unsigned short)(hv & 0xFFFF)), acc.x);
    acc.y = fmaf(v, bf2f((unsigned short)(hv >> 16)), acc.y);
    vsum += v;
  }
  unsigned int o = (unsigned int)f2bf(acc.x) | ((unsigned int)f2bf(acc.y) << 16);
  *(unsigned int*)(G + (size_t)row * 128 + lane * 2) = o;
  if (lane == 0) svec[row] = vsum;
}

__global__ __launch_bounds__(256) void spmm_kernel_256(
    const unsigned short* __restrict__ H, const int* __restrict__ rowstart,
    const uint2* __restrict__ edges, const float* __restrict__ dinv,
    unsigned short* __restrict__ G, int N)
{
  int wave = threadIdx.x >> 6, lane = threadIdx.x & 63;
  int row = blockIdx.x * 4 + wave;
  if (row >= N) return;
  const unsigned short* Hl = H + lane * 4;
  float dv = dinv[row];
  float self = dv * dv;
  uint2 sv0 = *(const uint2*)(Hl + (size_t)row * 256);
  float4 acc;
  acc.x = self * bf2f((unsigned short)(sv0.x & 0xFFFF));
  acc.y = self * bf2f((unsigned short)(sv0.x >> 16));
  acc.z = self * bf2f((unsigned short)(sv0.y & 0xFFFF));
  acc.w = self * bf2f((unsigned short)(sv0.y >> 16));
  int e0 = rowstart[row], e1 = rowstart[row + 1];
  int e = e0;
  for (; e + 8 <= e1; e += 8) {
    uint2 h[8]; float v[8];
    #pragma unroll
    for (int q = 0; q < 8; ++q) {
      uint2 pq = edges[e + q];
      v[q] = asf(pq.y);
      h[q] = *(const uint2*)(Hl + (size_t)pq.x * 256);
    }
    #pragma unroll
    for (int q = 0; q < 8; ++q) {
      acc.x = fmaf(v[q], bf2f((unsigned short)(h[q].x & 0xFFFF)), acc.x);
      acc.y = fmaf(v[q], bf2f((unsigned short)(h[q].x >> 16)), acc.y);
      acc.z = fmaf(v[q], bf2f((unsigned short)(h[q].y & 0xFFFF)), acc.z);
      acc.w = fmaf(v[q], bf2f((unsigned short)(h[q].y >> 16)), acc.w);
    }
  }
  for (; e < e1; ++e) {
    uint2 p = edges[e];
    float v = asf(p.y);
    uint2 hv = *(const uint2*)(Hl + (size_t)p.x * 256);
    acc.x = fmaf(v, bf2f((unsigned short)(hv.x & 0xFFFF)), acc.x);
    acc.y = fmaf(v, bf2f((unsigned short)(hv.x >> 16)), acc.y);
    acc.z = fmaf(v, bf2f((unsigned short)(hv.y & 0xFFFF)), acc.z);
    acc.w = fmaf(v, bf2f((unsigned short)(hv.y >> 16)), acc.w);
  }
  uint2 o;
  o.x = (unsigned int)f2bf(acc.x) | ((unsigned int)f2bf(acc.y) << 16);
  o.y = (unsigned int)f2bf(acc.z) | ((unsigned int)f2bf(acc.w) << 16);
  *(uint2*)(G + (size_t)row * 256 + lane * 4) = o;
}

// ---------------------------------------------------------------- MFMA GEMM + bias + leaky-relu
// out[M,256] = act(A[M,K](bf16) @ (WtHi+WtLo)^T + bias + USES*s[i]*c[n]), bf16 out.
// K is compile-time: kc loop fully unrolled so the compiler software-pipelines
// the global loads across iterations (vmcnt-counted prefetch).

template<int K, int USES>
__global__ __launch_bounds__(256) void gemm_mfma(
    const unsigned short* __restrict__ A, const unsigned short* __restrict__ WtHi,
    const unsigned short* __restrict__ WtLo, const float* __restrict__ bias,
    const float* __restrict__ s, const float* __restrict__ c,
    unsigned short* __restrict__ out, int M)
{
  int wv = threadIdx.x >> 6, l = threadIdx.x & 63;
  int lr = l & 15, lg = l >> 4;
  int row0 = blockIdx.x * 128 + (wv >> 1) * 64;
  int col0 = blockIdx.y * 128 + (wv & 1) * 64;

  const unsigned short* Ap  = A    + (size_t)(row0 + lr) * K + lg * 8;
  const unsigned short* Bhp = WtHi + (size_t)(col0 + lr) * K + lg * 8;
  const unsigned short* Blp = WtLo + (size_t)(col0 + lr) * K + lg * 8;

  f32x4 acc[4][4];
  #pragma unroll
  for (int i = 0; i < 4; ++i)
    #pragma unroll
    for (int j = 0; j < 4; ++j)
      acc[i][j] = (f32x4){0.f, 0.f, 0.f, 0.f};

  #pragma unroll
  for (int kc = 0; kc < K; kc += 32) {
    bf16x8 a[4], bh[4], bl[4];
    #pragma unroll
    for (int fi = 0; fi < 4; ++fi)
      a[fi] = *(const bf16x8*)(Ap + (size_t)(fi * 16) * K + kc);
    #pragma unroll
    for (int fj = 0; fj < 4; ++fj) {
      bh[fj] = *(const bf16x8*)(Bhp + (size_t)(fj * 16) * K + kc);
      bl[fj] = *(const bf16x8*)(Blp + (size_t)(fj * 16) * K + kc);
    }
    #pragma unroll
    for (int fi = 0; fi < 4; ++fi)
      #pragma unroll
      for (int fj = 0; fj < 4; ++fj) {
        acc[fi][fj] = __builtin_amdgcn_mfma_f32_16x16x32_bf16(a[fi], bh[fj], acc[fi][fj], 0, 0, 0);
        acc[fi][fj] = __builtin_amdgcn_mfma_f32_16x16x32_bf16(a[fi], bl[fj], acc[fi][fj], 0, 0, 0);
      }
  }

  float bb[4], cv[4];
  #pragma unroll
  for (int fj = 0; fj < 4; ++fj) {
    int colj = col0 + fj * 16 + lr;
    bb[fj] = bias[colj];
    cv[fj] = USES ? c[colj] : 0.0f;
  }
  #pragma unroll
  for (int fi = 0; fi < 4; ++fi) {
    #pragma unroll
    for (int r = 0; r < 4; ++r) {
      int row = row0 + fi * 16 + lg * 4 + r;
      if (row < M) {
        float sv = USES ? s[row] : 0.0f;
        #pragma unroll
        for (int fj = 0; fj < 4; ++fj) {
          float v = acc[fi][fj][r] + bb[fj] + sv * cv[fj];
          v = v > 0.0f ? v : 0.01f * v;
          out[(size_t)row * 256 + col0 + fj * 16 + lr] = f2bf(v);
        }
      }
    }
  }
}

// ---------------------------------------------------------------- pooling + head

__global__ void colsum_kernel(const unsigned short* __restrict__ H, float* __restrict__ pooled, int N) {
  int t = threadIdx.x;
  float acc = 0.f;
  for (int r = blockIdx.x; r < N; r += gridDim.x)
    acc += bf2f(H[(size_t)r * 256 + t]);
  atomicAdd(&pooled[t], acc);
}

__global__ void final_kernel(const float* __restrict__ pooled, const float* __restrict__ Wlin,
                             const float* __restrict__ blin, float* __restrict__ out, float invN) {
  __shared__ float sd[256];
  int t = threadIdx.x;
  sd[t] = pooled[t] * invN * Wlin[t];
  __syncthreads();
  for (int off = 128; off > 0; off >>= 1) {
    if (t < off) sd[t] += sd[t + off];
    __syncthreads();
  }
  if (t == 0) out[0] = sd[0] + blin[0];
}

// ---------------------------------------------------------------- launch

extern "C" void kernel_launch(void* const* d_in, const int* in_sizes, int n_in,
                              void* d_out, int out_size, void* d_ws, size_t ws_size,
                              hipStream_t stream) {
  const float* x    = (const float*)d_in[0];
  const int*   ei   = (const int*)d_in[1];     // int32 on the wire
  const float* u    = (const float*)d_in[2];
  const float* w    = (const float*)d_in[3];
  const float* W1   = (const float*)d_in[4];  const float* b1 = (const float*)d_in[5];
  const float* W2   = (const float*)d_in[6];  const float* b2 = (const float*)d_in[7];
  const float* W3   = (const float*)d_in[8];  const float* b3 = (const float*)d_in[9];
  const float* W4   = (const float*)d_in[10]; const float* b4 = (const float*)d_in[11];
  const float* W5   = (const float*)d_in[12]; const float* b5 = (const float*)d_in[13];
  const float* Wlin = (const float*)d_in[14]; const float* blin = (const float*)d_in[15];

  int N = in_sizes[0] / F_IN;
  int E = in_sizes[1] / 2;
  int Npad = (N + 127) & ~127;
  const int* srcp = ei;
  const int* dstp = ei + E;

  char* p = (char*)d_ws;
  auto alloc = [&](size_t bytes) { char* r = p; p += (bytes + 255) & ~(size_t)255; return r; };
  unsigned short* bufH = (unsigned short*)alloc((size_t)Npad * 256 * 2);  // bf16 hidden
  unsigned short* bufG = (unsigned short*)alloc((size_t)Npad * 256 * 2);  // bf16 aggregate
  uint2* edges    = (uint2*)alloc((size_t)E * 8);                         // (col, val) pairs
  int*   cnt      = (int*)alloc((size_t)N * 4);
  float* dinv     = (float*)alloc((size_t)N * 4);
  int*   rowstart = (int*)alloc((size_t)(N + 1) * 4);
  int*   cursor   = (int*)alloc((size_t)N * 4);
  float* svec     = (float*)alloc((size_t)N * 4);
  float* cvec     = (float*)alloc(256 * 4);
  int*   blocksum = (int*)alloc(128 * 4);
  int*   blockoff = (int*)alloc(128 * 4);
  float* pooled   = (float*)alloc(256 * 4);
  // transposed hi/lo weight planes: [256 cols][K]
  unsigned short* wt1h = (unsigned short*)alloc(256 * 128 * 2);
  unsigned short* wt1l = (unsigned short*)alloc(256 * 128 * 2);
  unsigned short* wth[4]; unsigned short* wtl[4];
  for (int i = 0; i < 4; ++i) {
    wth[i] = (unsigned short*)alloc(256 * 256 * 2);
    wtl[i] = (unsigned short*)alloc(256 * 256 * 2);
  }

  hipMemsetAsync(cnt, 0, (size_t)N * 4, stream);
  hipMemsetAsync(pooled, 0, 256 * 4, stream);
  // zero A-pad rows (read by gemm fragment loads): 128-wide and 256-wide regions of bufG
  hipMemsetAsync(bufG + (size_t)N * 128, 0, (size_t)(Npad - N) * 128 * 2, stream);
  hipMemsetAsync(bufG + (size_t)N * 256, 0, (size_t)(Npad - N) * 256 * 2, stream);

  const int tpb = 256;
  hist_kernel<<<(E + tpb - 1) / tpb, tpb, 0, stream>>>(dstp, E, cnt);
  dinv_kernel<<<(N + tpb - 1) / tpb, tpb, 0, stream>>>(cnt, dinv, N);
  int nblk = (N + 1023) / 1024;
  scan_local<<<nblk, 1024, 0, stream>>>(cnt, rowstart, blocksum, N);
  scan_blk<<<1, 128, 0, stream>>>(blocksum, blockoff, nblk);
  scan_add<<<(N + tpb - 1) / tpb, tpb, 0, stream>>>(rowstart, blockoff, cursor, N, E);
  fill_csr<<<(E + tpb - 1) / tpb, tpb, 0, stream>>>(srcp, dstp, dinv, cursor, edges, E);
  c_kernel<<<1, 256, 0, stream>>>(W1, u, w, cvec);

  wt_split<<<(128 * 256 + tpb - 1) / tpb, tpb, 0, stream>>>(W1, wt1h, wt1l, 128);
  const float* Ws[4] = {W2, W3, W4, W5};
  const float* bs[4] = {b2, b3, b4, b5};
  for (int i = 0; i < 4; ++i)
    wt_split<<<(256 * 256 + tpb - 1) / tpb, tpb, 0, stream>>>(Ws[i], wth[i], wtl[i], 256);

  long long nx = (long long)N * 128;
  padx_kernel<<<(int)((nx + tpb - 1) / tpb), tpb, 0, stream>>>(x, bufH, N);

  dim3 ggrid(Npad / 128, 2);
  // layer 1: aggregate at width 128 (bf16), transform 128->256 with s*c epilogue
  spmm_kernel_128<<<(N + 3) / 4, 256, 0, stream>>>(bufH, rowstart, edges, dinv, bufG, svec, N);
  gemm_mfma<128, 1><<<ggrid, 256, 0, stream>>>(bufG, wt1h, wt1l, b1, svec, cvec, bufH, N);

  for (int l = 0; l < 4; ++l) {
    spmm_kernel_256<<<(N + 3) / 4, 256, 0, stream>>>(bufH, rowstart, edges, dinv, bufG, N);
    gemm_mfma<256, 0><<<ggrid, 256, 0, stream>>>(bufG, wth[l], wtl[l], bs[l], svec, cvec, bufH, N);
  }

  colsum_kernel<<<2048, 256, 0, stream>>>(bufH, pooled, N);
  final_kernel<<<1, 256, 0, stream>>>(pooled, Wlin, blin, (float*)d_out, 1.0f / (float)N);
}

// Round 11
// 1130.811 us; speedup vs baseline: 2.0349x; 1.1692x over previous
//
#include <hip/hip_runtime.h>
#include <hip/hip_bf16.h>
#include <cstdint>
#include <cstddef>

#define F_IN 126
#define HID 256

typedef __attribute__((ext_vector_type(8))) short bf16x8;
typedef __attribute__((ext_vector_type(4))) float f32x4;
typedef __attribute__((ext_vector_type(2))) float f32x2;

// bf16 storage helpers (arithmetic stays fp32)
__device__ __forceinline__ float bf2f(unsigned short u) {
  union { unsigned int i; float f; } v; v.i = ((unsigned int)u) << 16; return v.f;
}
__device__ __forceinline__ unsigned short f2bf(float x) {
  union { float f; unsigned int i; } v; v.f = x;
  unsigned int b = v.i + 0x7FFFu + ((v.i >> 16) & 1u);  // round-to-nearest-even
  return (unsigned short)(b >> 16);
}
__device__ __forceinline__ float asf(unsigned int u) {
  union { unsigned int i; float f; } v; v.i = u; return v.f;
}
// fp8 e4m3 (hardware cvt, RNE)
__device__ __forceinline__ unsigned char f2fp8(float x) {
  int p = __builtin_amdgcn_cvt_pk_fp8_f32(x, x, 0, false);
  return (unsigned char)(p & 0xFF);
}

// ---------------------------------------------------------------- graph prep

__global__ void hist_kernel(const int* __restrict__ dst, int E, int* __restrict__ cnt) {
  int e = blockIdx.x * blockDim.x + threadIdx.x;
  if (e < E) atomicAdd(&cnt[dst[e]], 1);
}

__global__ void dinv_kernel(const int* __restrict__ cnt, float* __restrict__ dinv, int N) {
  int i = blockIdx.x * blockDim.x + threadIdx.x;
  if (i < N) dinv[i] = rsqrtf((float)(cnt[i] + 1));  // self-loop => deg >= 1
}

__global__ void scan_local(const int* __restrict__ cnt, int* __restrict__ rowstart,
                           int* __restrict__ blocksum, int N) {
  __shared__ int sd[1024];
  int t = threadIdx.x;
  int gi = blockIdx.x * 1024 + t;
  int v = (gi < N) ? cnt[gi] : 0;
  sd[t] = v;
  __syncthreads();
  for (int off = 1; off < 1024; off <<= 1) {
    int add = (t >= off) ? sd[t - off] : 0;
    __syncthreads();
    sd[t] += add;
    __syncthreads();
  }
  if (gi < N) rowstart[gi] = sd[t] - v;
  if (t == 1023) blocksum[blockIdx.x] = sd[1023];
}

__global__ void scan_blk(const int* __restrict__ blocksum, int* __restrict__ blockoff, int nblk) {
  __shared__ int sd[128];
  int t = threadIdx.x;
  int v = (t < nblk) ? blocksum[t] : 0;
  sd[t] = v;
  __syncthreads();
  for (int off = 1; off < 128; off <<= 1) {
    int add = (t >= off) ? sd[t - off] : 0;
    __syncthreads();
    sd[t] += add;
    __syncthreads();
  }
  if (t < nblk) blockoff[t] = sd[t] - v;
}

__global__ void scan_add(int* __restrict__ rowstart, const int* __restrict__ blockoff,
                         int* __restrict__ cursor, int N, int E) {
  int i = blockIdx.x * blockDim.x + threadIdx.x;
  if (i < N) {
    int r = rowstart[i] + blockoff[i >> 10];
    rowstart[i] = r;
    cursor[i] = r;
  }
  if (i == 0) rowstart[N] = E;
}

// edges: interleaved (col, val-bits) pairs, one 8B load per edge in SpMM
__global__ void fill_csr(const int* __restrict__ srcp, const int* __restrict__ dstp,
                         const float* __restrict__ dinv, int* __restrict__ cursor,
                         uint2* __restrict__ edges, int E) {
  int e = blockIdx.x * blockDim.x + threadIdx.x;
  if (e >= E) return;
  int s = srcp[e];
  int d = dstp[e];
  int pos = atomicAdd(&cursor[d], 1);
  float v = dinv[s] * dinv[d];
  union { float f; unsigned int i; } vv; vv.f = v;
  edges[pos] = make_uint2((unsigned int)s, vv.i);
}

// c[n] = u*W1[126,n] + w*W1[127,n]
__global__ void c_kernel(const float* __restrict__ W1, const float* __restrict__ up,
                         const float* __restrict__ wp, float* __restrict__ c) {
  int n = threadIdx.x;
  c[n] = up[0] * W1[126 * 256 + n] + wp[0] * W1[127 * 256 + n];
}

// W [K,256] fp32 -> WtHi/WtLo [256,K] bf16 (transposed, hi + residual-lo split)
__global__ void wt_split(const float* __restrict__ W, unsigned short* __restrict__ wthi,
                         unsigned short* __restrict__ wtlo, int K) {
  int i = blockIdx.x * blockDim.x + threadIdx.x;
  if (i >= K * 256) return;
  int k = i >> 8, n = i & 255;
  float wv = W[(size_t)k * 256 + n];
  unsigned short hi = f2bf(wv);
  float r = wv - bf2f(hi);
  wthi[(size_t)n * K + k] = hi;
  wtlo[(size_t)n * K + k] = f2bf(r);
}

// x [N,126] fp32 -> X [N,128] fp8, zero-padded
__global__ void padx_kernel(const float* __restrict__ x, unsigned char* __restrict__ X, int N) {
  long long i = (long long)blockIdx.x * blockDim.x + threadIdx.x;
  if (i >= (long long)N * 128) return;
  int r = (int)(i >> 7), f = (int)(i & 127);
  X[i] = (f < F_IN) ? f2fp8(x[(size_t)r * F_IN + f]) : (unsigned char)0;
}

// ---------------------------------------------------------------- SpMM (CSR, wave per row, fp8 in, bf16 out, fp32 accum)
// 8x unrolled edge loop; fp8 rows halve gather traffic vs bf16.

__global__ __launch_bounds__(256) void spmm_kernel_128(
    const unsigned char* __restrict__ H, const int* __restrict__ rowstart,
    const uint2* __restrict__ edges, const float* __restrict__ dinv,
    unsigned short* __restrict__ G, float* __restrict__ svec, int N)
{
  int wave = threadIdx.x >> 6, lane = threadIdx.x & 63;
  int row = blockIdx.x * 4 + wave;
  if (row >= N) return;
  const unsigned char* Hl = H + lane * 2;
  float dv = dinv[row];
  float self = dv * dv;
  unsigned int sv0 = *(const unsigned short*)(Hl + (size_t)row * 128);
  f32x2 sf = __builtin_amdgcn_cvt_pk_f32_fp8(sv0, false);
  float2 acc;
  acc.x = self * sf.x;
  acc.y = self * sf.y;
  float vsum = self;
  int e0 = rowstart[row], e1 = rowstart[row + 1];
  int e = e0;
  for (; e + 8 <= e1; e += 8) {
    unsigned int h[8]; float v[8];
    #pragma unroll
    for (int q = 0; q < 8; ++q) {
      uint2 pq = edges[e + q];
      v[q] = asf(pq.y);
      h[q] = *(const unsigned short*)(Hl + (size_t)pq.x * 128);
    }
    #pragma unroll
    for (int q = 0; q < 8; ++q) {
      f32x2 f = __builtin_amdgcn_cvt_pk_f32_fp8(h[q], false);
      acc.x = fmaf(v[q], f.x, acc.x);
      acc.y = fmaf(v[q], f.y, acc.y);
      vsum += v[q];
    }
  }
  for (; e < e1; ++e) {
    uint2 p = edges[e];
    float v = asf(p.y);
    unsigned int hv = *(const unsigned short*)(Hl + (size_t)p.x * 128);
    f32x2 f = __builtin_amdgcn_cvt_pk_f32_fp8(hv, false);
    acc.x = fmaf(v, f.x, acc.x);
    acc.y = fmaf(v, f.y, acc.y);
    vsum += v;
  }
  unsigned int o = (unsigned int)f2bf(acc.x) | ((unsigned int)f2bf(acc.y) << 16);
  *(unsigned int*)(G + (size_t)row * 128 + lane * 2) = o;
  if (lane == 0) svec[row] = vsum;
}

__global__ __launch_bounds__(256) void spmm_kernel_256(
    const unsigned char* __restrict__ H, const int* __restrict__ rowstart,
    const uint2* __restrict__ edges, const float* __restrict__ dinv,
    unsigned short* __restrict__ G, int N)
{
  int wave = threadIdx.x >> 6, lane = threadIdx.x & 63;
  int row = blockIdx.x * 4 + wave;
  if (row >= N) return;
  const unsigned char* Hl = H + lane * 4;
  float dv = dinv[row];
  float self = dv * dv;
  unsigned int sv0 = *(const unsigned int*)(Hl + (size_t)row * 256);
  f32x2 slo = __builtin_amdgcn_cvt_pk_f32_fp8(sv0, false);
  f32x2 shi = __builtin_amdgcn_cvt_pk_f32_fp8(sv0, true);
  float4 acc;
  acc.x = self * slo.x;
  acc.y = self * slo.y;
  acc.z = self * shi.x;
  acc.w = self * shi.y;
  int e0 = rowstart[row], e1 = rowstart[row + 1];
  int e = e0;
  for (; e + 8 <= e1; e += 8) {
    unsigned int h[8]; float v[8];
    #pragma unroll
    for (int q = 0; q < 8; ++q) {
      uint2 pq = edges[e + q];
      v[q] = asf(pq.y);
      h[q] = *(const unsigned int*)(Hl + (size_t)pq.x * 256);
    }
    #pragma unroll
    for (int q = 0; q < 8; ++q) {
      f32x2 lo = __builtin_amdgcn_cvt_pk_f32_fp8(h[q], false);
      f32x2 hi = __builtin_amdgcn_cvt_pk_f32_fp8(h[q], true);
      acc.x = fmaf(v[q], lo.x, acc.x);
      acc.y = fmaf(v[q], lo.y, acc.y);
      acc.z = fmaf(v[q], hi.x, acc.z);
      acc.w = fmaf(v[q], hi.y, acc.w);
    }
  }
  for (; e < e1; ++e) {
    uint2 p = edges[e];
    float v = asf(p.y);
    unsigned int hv = *(const unsigned int*)(Hl + (size_t)p.x * 256);
    f32x2 lo = __builtin_amdgcn_cvt_pk_f32_fp8(hv, false);
    f32x2 hi = __builtin_amdgcn_cvt_pk_f32_fp8(hv, true);
    acc.x = fmaf(v, lo.x, acc.x);
    acc.y = fmaf(v, lo.y, acc.y);
    acc.z = fmaf(v, hi.x, acc.z);
    acc.w = fmaf(v, hi.y, acc.w);
  }
  uint2 o;
  o.x = (unsigned int)f2bf(acc.x) | ((unsigned int)f2bf(acc.y) << 16);
  o.y = (unsigned int)f2bf(acc.z) | ((unsigned int)f2bf(acc.w) << 16);
  *(uint2*)(G + (size_t)row * 256 + lane * 4) = o;
}

// ---------------------------------------------------------------- MFMA GEMM + bias + leaky-relu
// out[M,256] = act(A[M,K](bf16) @ (WtHi+WtLo)^T + bias + USES*s[i]*c[n]).
// OUT8=1 -> fp8 output (gathered layers); OUT8=0 -> bf16 (final layer, feeds pooling).

template<int K, int USES, int OUT8>
__global__ __launch_bounds__(256) void gemm_mfma(
    const unsigned short* __restrict__ A, const unsigned short* __restrict__ WtHi,
    const unsigned short* __restrict__ WtLo, const float* __restrict__ bias,
    const float* __restrict__ s, const float* __restrict__ c,
    unsigned char* __restrict__ out8, unsigned short* __restrict__ out16, int M)
{
  int wv = threadIdx.x >> 6, l = threadIdx.x & 63;
  int lr = l & 15, lg = l >> 4;
  int row0 = blockIdx.x * 128 + (wv >> 1) * 64;
  int col0 = blockIdx.y * 128 + (wv & 1) * 64;

  const unsigned short* Ap  = A    + (size_t)(row0 + lr) * K + lg * 8;
  const unsigned short* Bhp = WtHi + (size_t)(col0 + lr) * K + lg * 8;
  const unsigned short* Blp = WtLo + (size_t)(col0 + lr) * K + lg * 8;

  f32x4 acc[4][4];
  #pragma unroll
  for (int i = 0; i < 4; ++i)
    #pragma unroll
    for (int j = 0; j < 4; ++j)
      acc[i][j] = (f32x4){0.f, 0.f, 0.f, 0.f};

  #pragma unroll
  for (int kc = 0; kc < K; kc += 32) {
    bf16x8 a[4], bh[4], bl[4];
    #pragma unroll
    for (int fi = 0; fi < 4; ++fi)
      a[fi] = *(const bf16x8*)(Ap + (size_t)(fi * 16) * K + kc);
    #pragma unroll
    for (int fj = 0; fj < 4; ++fj) {
      bh[fj] = *(const bf16x8*)(Bhp + (size_t)(fj * 16) * K + kc);
      bl[fj] = *(const bf16x8*)(Blp + (size_t)(fj * 16) * K + kc);
    }
    #pragma unroll
    for (int fi = 0; fi < 4; ++fi)
      #pragma unroll
      for (int fj = 0; fj < 4; ++fj) {
        acc[fi][fj] = __builtin_amdgcn_mfma_f32_16x16x32_bf16(a[fi], bh[fj], acc[fi][fj], 0, 0, 0);
        acc[fi][fj] = __builtin_amdgcn_mfma_f32_16x16x32_bf16(a[fi], bl[fj], acc[fi][fj], 0, 0, 0);
      }
  }

  float bb[4], cv[4];
  #pragma unroll
  for (int fj = 0; fj < 4; ++fj) {
    int colj = col0 + fj * 16 + lr;
    bb[fj] = bias[colj];
    cv[fj] = USES ? c[colj] : 0.0f;
  }
  #pragma unroll
  for (int fi = 0; fi < 4; ++fi) {
    #pragma unroll
    for (int r = 0; r < 4; ++r) {
      int row = row0 + fi * 16 + lg * 4 + r;
      if (row < M) {
        float sv = USES ? s[row] : 0.0f;
        #pragma unroll
        for (int fj = 0; fj < 4; ++fj) {
          float v = acc[fi][fj][r] + bb[fj] + sv * cv[fj];
          v = v > 0.0f ? v : 0.01f * v;
          int col = col0 + fj * 16 + lr;
          if (OUT8) out8[(size_t)row * 256 + col] = f2fp8(v);
          else      out16[(size_t)row * 256 + col] = f2bf(v);
        }
      }
    }
  }
}

// ---------------------------------------------------------------- pooling + head

__global__ void colsum_kernel(const unsigned short* __restrict__ H, float* __restrict__ pooled, int N) {
  int t = threadIdx.x;
  float acc = 0.f;
  for (int r = blockIdx.x; r < N; r += gridDim.x)
    acc += bf2f(H[(size_t)r * 256 + t]);
  atomicAdd(&pooled[t], acc);
}

__global__ void final_kernel(const float* __restrict__ pooled, const float* __restrict__ Wlin,
                             const float* __restrict__ blin, float* __restrict__ out, float invN) {
  __shared__ float sd[256];
  int t = threadIdx.x;
  sd[t] = pooled[t] * invN * Wlin[t];
  __syncthreads();
  for (int off = 128; off > 0; off >>= 1) {
    if (t < off) sd[t] += sd[t + off];
    __syncthreads();
  }
  if (t == 0) out[0] = sd[0] + blin[0];
}

// ---------------------------------------------------------------- launch

extern "C" void kernel_launch(void* const* d_in, const int* in_sizes, int n_in,
                              void* d_out, int out_size, void* d_ws, size_t ws_size,
                              hipStream_t stream) {
  const float* x    = (const float*)d_in[0];
  const int*   ei   = (const int*)d_in[1];     // int32 on the wire
  const float* u    = (const float*)d_in[2];
  const float* w    = (const float*)d_in[3];
  const float* W1   = (const float*)d_in[4];  const float* b1 = (const float*)d_in[5];
  const float* W2   = (const float*)d_in[6];  const float* b2 = (const float*)d_in[7];
  const float* W3   = (const float*)d_in[8];  const float* b3 = (const float*)d_in[9];
  const float* W4   = (const float*)d_in[10]; const float* b4 = (const float*)d_in[11];
  const float* W5   = (const float*)d_in[12]; const float* b5 = (const float*)d_in[13];
  const float* Wlin = (const float*)d_in[14]; const float* blin = (const float*)d_in[15];

  int N = in_sizes[0] / F_IN;
  int E = in_sizes[1] / 2;
  int Npad = (N + 127) & ~127;
  const int* srcp = ei;
  const int* dstp = ei + E;

  char* p = (char*)d_ws;
  auto alloc = [&](size_t bytes) { char* r = p; p += (bytes + 255) & ~(size_t)255; return r; };
  unsigned char*  bufH8 = (unsigned char*)alloc((size_t)Npad * 256);      // fp8 hidden (layers 1-4) / padded x (width 128 uses first half)
  unsigned short* bufHb = (unsigned short*)alloc((size_t)Npad * 256 * 2); // bf16 hidden (final layer only)
  unsigned short* bufG  = (unsigned short*)alloc((size_t)Npad * 256 * 2); // bf16 aggregate
  unsigned char*  bufX8 = (unsigned char*)alloc((size_t)Npad * 128);      // fp8 padded input
  uint2* edges    = (uint2*)alloc((size_t)E * 8);                         // (col, val) pairs
  int*   cnt      = (int*)alloc((size_t)N * 4);
  float* dinv     = (float*)alloc((size_t)N * 4);
  int*   rowstart = (int*)alloc((size_t)(N + 1) * 4);
  int*   cursor   = (int*)alloc((size_t)N * 4);
  float* svec     = (float*)alloc((size_t)N * 4);
  float* cvec     = (float*)alloc(256 * 4);
  int*   blocksum = (int*)alloc(128 * 4);
  int*   blockoff = (int*)alloc(128 * 4);
  float* pooled   = (float*)alloc(256 * 4);
  // transposed hi/lo weight planes: [256 cols][K]
  unsigned short* wt1h = (unsigned short*)alloc(256 * 128 * 2);
  unsigned short* wt1l = (unsigned short*)alloc(256 * 128 * 2);
  unsigned short* wth[4]; unsigned short* wtl[4];
  for (int i = 0; i < 4; ++i) {
    wth[i] = (unsigned short*)alloc(256 * 256 * 2);
    wtl[i] = (unsigned short*)alloc(256 * 256 * 2);
  }

  hipMemsetAsync(cnt, 0, (size_t)N * 4, stream);
  hipMemsetAsync(pooled, 0, 256 * 4, stream);
  // zero A-pad rows (read by gemm fragment loads): 128-wide and 256-wide regions of bufG
  hipMemsetAsync(bufG + (size_t)N * 128, 0, (size_t)(Npad - N) * 128 * 2, stream);
  hipMemsetAsync(bufG + (size_t)N * 256, 0, (size_t)(Npad - N) * 256 * 2, stream);

  const int tpb = 256;
  hist_kernel<<<(E + tpb - 1) / tpb, tpb, 0, stream>>>(dstp, E, cnt);
  dinv_kernel<<<(N + tpb - 1) / tpb, tpb, 0, stream>>>(cnt, dinv, N);
  int nblk = (N + 1023) / 1024;
  scan_local<<<nblk, 1024, 0, stream>>>(cnt, rowstart, blocksum, N);
  scan_blk<<<1, 128, 0, stream>>>(blocksum, blockoff, nblk);
  scan_add<<<(N + tpb - 1) / tpb, tpb, 0, stream>>>(rowstart, blockoff, cursor, N, E);
  fill_csr<<<(E + tpb - 1) / tpb, tpb, 0, stream>>>(srcp, dstp, dinv, cursor, edges, E);
  c_kernel<<<1, 256, 0, stream>>>(W1, u, w, cvec);

  wt_split<<<(128 * 256 + tpb - 1) / tpb, tpb, 0, stream>>>(W1, wt1h, wt1l, 128);
  const float* Ws[4] = {W2, W3, W4, W5};
  const float* bs[4] = {b2, b3, b4, b5};
  for (int i = 0; i < 4; ++i)
    wt_split<<<(256 * 256 + tpb - 1) / tpb, tpb, 0, stream>>>(Ws[i], wth[i], wtl[i], 256);

  long long nx = (long long)N * 128;
  padx_kernel<<<(int)((nx + tpb - 1) / tpb), tpb, 0, stream>>>(x, bufX8, N);

  dim3 ggrid(Npad / 128, 2);
  // layer 1: aggregate at width 128 (fp8 gather), transform 128->256 with s*c epilogue, fp8 out
  spmm_kernel_128<<<(N + 3) / 4, 256, 0, stream>>>(bufX8, rowstart, edges, dinv, bufG, svec, N);
  gemm_mfma<128, 1, 1><<<ggrid, 256, 0, stream>>>(bufG, wt1h, wt1l, b1, svec, cvec, bufH8, bufHb, N);

  // layers 2-4: fp8 gather -> bf16 aggregate -> fp8 out
  for (int l = 0; l < 3; ++l) {
    spmm_kernel_256<<<(N + 3) / 4, 256, 0, stream>>>(bufH8, rowstart, edges, dinv, bufG, N);
    gemm_mfma<256, 0, 1><<<ggrid, 256, 0, stream>>>(bufG, wth[l], wtl[l], bs[l], svec, cvec, bufH8, bufHb, N);
  }
  // layer 5: bf16 out (feeds pooling directly — keep full storage precision)
  spmm_kernel_256<<<(N + 3) / 4, 256, 0, stream>>>(bufH8, rowstart, edges, dinv, bufG, N);
  gemm_mfma<256, 0, 0><<<ggrid, 256, 0, stream>>>(bufG, wth[3], wtl[3], bs[3], svec, cvec, bufH8, bufHb, N);

  colsum_kernel<<<2048, 256, 0, stream>>>(bufHb, pooled, N);
  final_kernel<<<1, 256, 0, stream>>>(pooled, Wlin, blin, (float*)d_out, 1.0f / (float)N);
}